// Round 1
// baseline (477.323 us; speedup 1.0000x reference)
//
#include <hip/hip_runtime.h>
#include <math.h>

#define PROWS 12800      // B*N rows per stream (B=2, N=6400)
#define NSEQ  6400
#define CDIM  96
#define DI    192
#define DSTATE 16
#define LC    64         // scan chunk length
#define NCHUNK 100       // NSEQ / LC

__device__ __forceinline__ float sigmoidf_(float x) { return 1.0f / (1.0f + __expf(-x)); }

// ---------------------------------------------------------------------------
// K1: LayerNorm both streams + token swap + channel shuffle.
//   x2s == x2n (swap is self-cancelling for stream 2); x1s = [x2n[:59], x1n[59:]]
//   shuffle: out[c'] = in[(c'&1)*48 + (c'>>1)]
// One 64-thread wave per row.
// ---------------------------------------------------------------------------
__global__ void ln_swap_shuffle(const float* __restrict__ x1, const float* __restrict__ x2,
                                const float* __restrict__ g1, const float* __restrict__ b1,
                                const float* __restrict__ g2, const float* __restrict__ b2,
                                float* __restrict__ XS) {
    int r = blockIdx.x;
    int t = threadIdx.x;          // 0..63
    __shared__ float a1[96], a2[96];

    float v10 = x1[r * 96 + t];
    float v20 = x2[r * 96 + t];
    float v11 = 0.f, v21 = 0.f;
    bool has2 = (t < 32);
    if (has2) { v11 = x1[r * 96 + t + 64]; v21 = x2[r * 96 + t + 64]; }

    float s1 = v10 + v11, s2 = v20 + v21;
    float q1 = v10 * v10 + v11 * v11, q2 = v20 * v20 + v21 * v21;
    for (int off = 1; off < 64; off <<= 1) {
        s1 += __shfl_xor(s1, off);
        q1 += __shfl_xor(q1, off);
        s2 += __shfl_xor(s2, off);
        q2 += __shfl_xor(q2, off);
    }
    const float inv96 = 1.0f / 96.0f;
    float m1 = s1 * inv96, m2 = s2 * inv96;
    float i1 = rsqrtf(q1 * inv96 - m1 * m1 + 1e-5f);
    float i2 = rsqrtf(q2 * inv96 - m2 * m2 + 1e-5f);

    a1[t] = (v10 - m1) * i1 * g1[t] + b1[t];
    a2[t] = (v20 - m2) * i2 * g2[t] + b2[t];
    if (has2) {
        a1[t + 64] = (v11 - m1) * i1 * g1[t + 64] + b1[t + 64];
        a2[t + 64] = (v21 - m2) * i2 * g2[t + 64] + b2[t + 64];
    }
    __syncthreads();

    for (int c = t; c < 96; c += 64) {
        int src = (c & 1) * 48 + (c >> 1);
        float vs2 = a2[src];
        float vs1 = (src < 59) ? vs2 : a1[src];
        XS[(size_t)r * 96 + c] = vs1;                       // stream 1 (m=0)
        XS[(size_t)PROWS * 96 + (size_t)r * 96 + c] = vs2;  // stream 2 (m=1)
    }
}

// ---------------------------------------------------------------------------
// Generic tiled GEMM: O[row,col] = sum_k X[row,k] * W[col,k] (+ R[row,col])
// X:[M,K] rowmajor, W:[N,K] rowmajor. 32x32 tile, 256 threads, 2x2/thread.
// blockIdx.z selects mamba (separate X/W/O/R pointers).
// Requires M,N,K multiples of 32.
// ---------------------------------------------------------------------------
__global__ void gemm_k(const float* __restrict__ X0, const float* __restrict__ X1,
                       const float* __restrict__ W0, const float* __restrict__ W1,
                       const float* __restrict__ R0, const float* __restrict__ R1,
                       float* __restrict__ O0, float* __restrict__ O1,
                       int M, int N, int K) {
    int m = blockIdx.z;
    const float* X = m ? X1 : X0;
    const float* W = m ? W1 : W0;
    const float* R = m ? R1 : R0;
    float* O = m ? O1 : O0;

    __shared__ float Xs[32][33];
    __shared__ float Ws[32][33];

    int tid = threadIdx.x;
    int tx = tid & 15, ty = tid >> 4;
    int row0 = blockIdx.x * 32, col0 = blockIdx.y * 32;

    float acc00 = 0.f, acc01 = 0.f, acc10 = 0.f, acc11 = 0.f;

    for (int kk = 0; kk < K; kk += 32) {
        for (int i = tid; i < 1024; i += 256) {
            int r = i >> 5, c = i & 31;
            Xs[r][c] = X[(size_t)(row0 + r) * K + kk + c];
            Ws[r][c] = W[(size_t)(col0 + r) * K + kk + c];
        }
        __syncthreads();
#pragma unroll
        for (int k = 0; k < 32; k++) {
            float a0 = Xs[ty * 2][k], a1 = Xs[ty * 2 + 1][k];
            float b0v = Ws[tx * 2][k], b1v = Ws[tx * 2 + 1][k];
            acc00 += a0 * b0v; acc01 += a0 * b1v;
            acc10 += a1 * b0v; acc11 += a1 * b1v;
        }
        __syncthreads();
    }

    int r0 = row0 + ty * 2, c0 = col0 + tx * 2;
    size_t i00 = (size_t)r0 * N + c0;
    size_t i10 = (size_t)(r0 + 1) * N + c0;
    if (R) {
        O[i00]     = acc00 + R[i00];
        O[i00 + 1] = acc01 + R[i00 + 1];
        O[i10]     = acc10 + R[i10];
        O[i10 + 1] = acc11 + R[i10 + 1];
    } else {
        O[i00] = acc00; O[i00 + 1] = acc01;
        O[i10] = acc10; O[i10 + 1] = acc11;
    }
}

// ---------------------------------------------------------------------------
// K3: depthwise causal conv1d (k=4, left pad 3) + bias + SiLU.
// XZ: [2][PROWS][384] (cols 0..191 = xc_raw). Writes XC: [2][PROWS][192]
// ---------------------------------------------------------------------------
__global__ void conv_silu(const float* __restrict__ XZ,
                          const float* __restrict__ cw0, const float* __restrict__ cw1,
                          const float* __restrict__ cb0, const float* __restrict__ cb1,
                          float* __restrict__ XC) {
    int idx = blockIdx.x * 256 + threadIdx.x;      // 2*PROWS*192 total
    int d = idx % DI;
    int r = (idx / DI) % PROWS;
    int m = idx / (DI * PROWS);
    int b = r / NSEQ, n = r % NSEQ;

    const float* cw = (m ? cw1 : cw0) + d * 4;
    float acc = (m ? cb1 : cb0)[d];
    const float* base = XZ + (size_t)m * PROWS * 384;
#pragma unroll
    for (int k = 0; k < 4; k++) {
        int nn = n - 3 + k;
        if (nn >= 0) acc += cw[k] * base[(size_t)(b * NSEQ + nn) * 384 + d];
    }
    XC[(size_t)m * PROWS * DI + (size_t)r * DI + d] = acc * sigmoidf_(acc);
}

// ---------------------------------------------------------------------------
// K4: per row: x_dbl = xproj_w @ xc_row (38 outputs); scatter Bm/Cm;
//     dt = softplus(dt_w @ x_dbl[:6] + dt_b). Block = 192 threads, 1 row.
// ---------------------------------------------------------------------------
__global__ void xdbl_dt(const float* __restrict__ XC,
                        const float* __restrict__ xp0, const float* __restrict__ xp1,
                        const float* __restrict__ dw0, const float* __restrict__ dw1,
                        const float* __restrict__ db0, const float* __restrict__ db1,
                        float* __restrict__ DT, float* __restrict__ BM, float* __restrict__ CM) {
    int r = blockIdx.x;
    int m = blockIdx.y;
    int tid = threadIdx.x;   // 0..191
    __shared__ float xrow[192];
    __shared__ float xdbl6[6];

    const float* XCm = XC + (size_t)m * PROWS * DI;
    xrow[tid] = XCm[(size_t)r * DI + tid];
    __syncthreads();

    if (tid < 76) {
        int o = tid >> 1, half = tid & 1;
        const float* w = (m ? xp1 : xp0) + o * DI + half * 96;
        const float* xr = &xrow[half * 96];
        float acc = 0.f;
#pragma unroll 8
        for (int j = 0; j < 96; j++) acc += w[j] * xr[j];
        acc += __shfl_xor(acc, 1);
        if (half == 0) {
            if (o < 6)       xdbl6[o] = acc;
            else if (o < 22) BM[(size_t)m * PROWS * DSTATE + (size_t)r * DSTATE + (o - 6)]  = acc;
            else             CM[(size_t)m * PROWS * DSTATE + (size_t)r * DSTATE + (o - 22)] = acc;
        }
    }
    __syncthreads();

    float acc = (m ? db1 : db0)[tid];
    const float* dw = (m ? dw1 : dw0) + tid * 6;
#pragma unroll
    for (int rr = 0; rr < 6; rr++) acc += dw[rr] * xdbl6[rr];
    float sp = fmaxf(acc, 0.f) + log1pf(expf(-fabsf(acc)));   // softplus
    DT[(size_t)m * PROWS * DI + (size_t)r * DI + tid] = sp;
}

// ---------------------------------------------------------------------------
// K5a: chunk-local scan (h_in = 0). Block = 256 = 16 d x 16 s; one chunk x
// 16-channel group per block. Stores h_end and sum(dt) per chunk.
// ---------------------------------------------------------------------------
__global__ void scan_phase1(const float* __restrict__ DT, const float* __restrict__ XC,
                            const float* __restrict__ BM,
                            const float* __restrict__ Al0, const float* __restrict__ Al1,
                            float* __restrict__ HEND, float* __restrict__ DTSUM) {
    int ck = blockIdx.x;      // chunk in [0,100)
    int dg = blockIdx.y;      // d-group in [0,12)
    int mb = blockIdx.z;      // m*2+b
    int m = mb >> 1, b = mb & 1;
    int tid = threadIdx.x;
    int dl = tid >> 4, s = tid & 15;
    int d = dg * 16 + dl;

    __shared__ float dtb[LC][16], xb[LC][16], Bb[LC][16];
    int r0 = b * NSEQ + ck * LC;
    const float* DTm = DT + (size_t)m * PROWS * DI;
    const float* XCm = XC + (size_t)m * PROWS * DI;
    const float* BMm = BM + (size_t)m * PROWS * DSTATE;
    for (int i = tid; i < LC * 16; i += 256) {
        int t = i >> 4, j = i & 15;
        dtb[t][j] = DTm[(size_t)(r0 + t) * DI + dg * 16 + j];
        xb[t][j]  = XCm[(size_t)(r0 + t) * DI + dg * 16 + j];
        Bb[t][j]  = BMm[(size_t)(r0 + t) * DSTATE + j];
    }
    __syncthreads();

    const float* Al = m ? Al1 : Al0;
    float a = -expf(Al[d * DSTATE + s]);
    float h = 0.f, dts = 0.f;
#pragma unroll 4
    for (int t = 0; t < LC; t++) {
        float dtv = dtb[t][dl];
        float xv  = xb[t][dl];
        float bv  = Bb[t][s];
        h = __expf(dtv * a) * h + dtv * xv * bv;
        dts += dtv;
    }
    HEND[(((size_t)mb * NCHUNK + ck) * DI + d) * DSTATE + s] = h;
    if (s == 0) DTSUM[((size_t)mb * NCHUNK + ck) * DI + d] = dts;
}

// ---------------------------------------------------------------------------
// K5b: sequential combine over chunks. thread <-> (m,b,d,s); 100 steps.
//   h_in[k] = exp(A * dtsum[k-1]) * h_in[k-1] + h_end[k-1]
// ---------------------------------------------------------------------------
__global__ void scan_combine(const float* __restrict__ HEND, const float* __restrict__ DTSUM,
                             const float* __restrict__ Al0, const float* __restrict__ Al1,
                             float* __restrict__ HIN) {
    int idx = blockIdx.x * 256 + threadIdx.x;  // 0..12287
    int s = idx & 15;
    int d = (idx >> 4) % DI;
    int mb = idx / (DI * DSTATE);
    int m = mb >> 1;
    const float* Al = m ? Al1 : Al0;
    float a = -expf(Al[d * DSTATE + s]);
    float h = 0.f;
    size_t base = (size_t)mb * NCHUNK;
    HIN[((base + 0) * DI + d) * DSTATE + s] = 0.f;
    for (int k = 1; k < NCHUNK; k++) {
        float dts = DTSUM[(base + k - 1) * DI + d];
        h = __expf(a * dts) * h + HEND[((base + k - 1) * DI + d) * DSTATE + s];
        HIN[((base + k) * DI + d) * DSTATE + s] = h;
    }
}

// ---------------------------------------------------------------------------
// K5c: chunk re-scan from h_in; y = sum_s h*C; fused D-skip + SiLU(z) gating.
// Writes YB: [2][PROWS][192]
// ---------------------------------------------------------------------------
__global__ void scan_phase3(const float* __restrict__ DT, const float* __restrict__ XC,
                            const float* __restrict__ BM, const float* __restrict__ CM,
                            const float* __restrict__ XZ,
                            const float* __restrict__ Al0, const float* __restrict__ Al1,
                            const float* __restrict__ D0, const float* __restrict__ D1,
                            const float* __restrict__ HIN, float* __restrict__ YB) {
    int ck = blockIdx.x;
    int dg = blockIdx.y;
    int mb = blockIdx.z;
    int m = mb >> 1, b = mb & 1;
    int tid = threadIdx.x;
    int dl = tid >> 4, s = tid & 15;
    int d = dg * 16 + dl;

    __shared__ float dtb[LC][16], xb[LC][16], Bb[LC][16], Cb[LC][16], zb[LC][16], yt[LC][16];
    int r0 = b * NSEQ + ck * LC;
    const float* DTm = DT + (size_t)m * PROWS * DI;
    const float* XCm = XC + (size_t)m * PROWS * DI;
    const float* BMm = BM + (size_t)m * PROWS * DSTATE;
    const float* CMm = CM + (size_t)m * PROWS * DSTATE;
    const float* XZm = XZ + (size_t)m * PROWS * 384;
    for (int i = tid; i < LC * 16; i += 256) {
        int t = i >> 4, j = i & 15;
        dtb[t][j] = DTm[(size_t)(r0 + t) * DI + dg * 16 + j];
        xb[t][j]  = XCm[(size_t)(r0 + t) * DI + dg * 16 + j];
        Bb[t][j]  = BMm[(size_t)(r0 + t) * DSTATE + j];
        Cb[t][j]  = CMm[(size_t)(r0 + t) * DSTATE + j];
        zb[t][j]  = XZm[(size_t)(r0 + t) * 384 + DI + dg * 16 + j];
    }
    __syncthreads();

    const float* Al = m ? Al1 : Al0;
    float a = -expf(Al[d * DSTATE + s]);
    float Dv = (m ? D1 : D0)[d];
    float h = HIN[(((size_t)mb * NCHUNK + ck) * DI + d) * DSTATE + s];

    for (int t = 0; t < LC; t++) {
        float dtv = dtb[t][dl];
        float xv  = xb[t][dl];
        float bv  = Bb[t][s];
        h = __expf(dtv * a) * h + dtv * xv * bv;
        float p = h * Cb[t][s];
        p += __shfl_xor(p, 1);
        p += __shfl_xor(p, 2);
        p += __shfl_xor(p, 4);
        p += __shfl_xor(p, 8);
        if (s == 0) {
            float zv = zb[t][dl];
            yt[t][dl] = (p + xv * Dv) * (zv * sigmoidf_(zv));
        }
    }
    __syncthreads();
    float* YBm = YB + (size_t)m * PROWS * DI;
    for (int i = tid; i < LC * 16; i += 256) {
        int t = i >> 4, j = i & 15;
        YBm[(size_t)(r0 + t) * DI + dg * 16 + j] = yt[t][j];
    }
}

// ---------------------------------------------------------------------------
extern "C" void kernel_launch(void* const* d_in, const int* in_sizes, int n_in,
                              void* d_out, int out_size, void* d_ws, size_t ws_size,
                              hipStream_t stream) {
    const float* x1    = (const float*)d_in[0];
    const float* x2    = (const float*)d_in[1];
    const float* ln1_g = (const float*)d_in[2];
    const float* ln1_b = (const float*)d_in[3];
    const float* ln2_g = (const float*)d_in[4];
    const float* ln2_b = (const float*)d_in[5];
    const float* e1_in_w    = (const float*)d_in[6];
    const float* e1_conv_w  = (const float*)d_in[7];
    const float* e1_conv_b  = (const float*)d_in[8];
    const float* e1_xproj_w = (const float*)d_in[9];
    const float* e1_dt_w    = (const float*)d_in[10];
    const float* e1_dt_b    = (const float*)d_in[11];
    const float* e1_A_log   = (const float*)d_in[12];
    const float* e1_D       = (const float*)d_in[13];
    const float* e1_out_w   = (const float*)d_in[14];
    const float* e2_in_w    = (const float*)d_in[15];
    const float* e2_conv_w  = (const float*)d_in[16];
    const float* e2_conv_b  = (const float*)d_in[17];
    const float* e2_xproj_w = (const float*)d_in[18];
    const float* e2_dt_w    = (const float*)d_in[19];
    const float* e2_dt_b    = (const float*)d_in[20];
    const float* e2_A_log   = (const float*)d_in[21];
    const float* e2_D       = (const float*)d_in[22];
    const float* e2_out_w   = (const float*)d_in[23];
    float* out = (float*)d_out;

    // workspace layout (floats)
    float* ws = (float*)d_ws;
    float* XS    = ws;                       // [2][P][96]    2,457,600
    float* XZ    = XS + 2457600;             // [2][P][384]   9,830,400
    float* XC    = XZ + 9830400;             // [2][P][192]   4,915,200
    float* DT    = XC + 4915200;             // [2][P][192]   4,915,200
    float* BM    = DT + 4915200;             // [2][P][16]      409,600
    float* CM    = BM + 409600;              // [2][P][16]      409,600
    float* YB    = CM + 409600;              // [2][P][192]   4,915,200
    float* HEND  = YB + 4915200;             // [4][100][192][16] 1,228,800
    float* DTSUM = HEND + 1228800;           // [4][100][192]   153,600
    float* HIN   = DTSUM + 153600;           // [4][100][192][16] 1,228,800

    // K1: LN + swap + shuffle
    ln_swap_shuffle<<<PROWS, 64, 0, stream>>>(x1, x2, ln1_g, ln1_b, ln2_g, ln2_b, XS);

    // K2: in-proj GEMM -> XZ  (M=12800, N=384, K=96)
    {
        dim3 g(PROWS / 32, 384 / 32, 2);
        gemm_k<<<g, 256, 0, stream>>>(XS, XS + (size_t)PROWS * 96,
                                      e1_in_w, e2_in_w,
                                      nullptr, nullptr,
                                      XZ, XZ + (size_t)PROWS * 384,
                                      PROWS, 384, 96);
    }

    // K3: conv + SiLU -> XC
    conv_silu<<<(2 * PROWS * DI) / 256, 256, 0, stream>>>(XZ, e1_conv_w, e2_conv_w,
                                                          e1_conv_b, e2_conv_b, XC);

    // K4: x_dbl + dt -> DT, BM, CM
    {
        dim3 g(PROWS, 2, 1);
        xdbl_dt<<<g, 192, 0, stream>>>(XC, e1_xproj_w, e2_xproj_w,
                                       e1_dt_w, e2_dt_w, e1_dt_b, e2_dt_b,
                                       DT, BM, CM);
    }

    // K5: chunked scan
    {
        dim3 g1(NCHUNK, DI / 16, 4);
        scan_phase1<<<g1, 256, 0, stream>>>(DT, XC, BM, e1_A_log, e2_A_log, HEND, DTSUM);
        scan_combine<<<48, 256, 0, stream>>>(HEND, DTSUM, e1_A_log, e2_A_log, HIN);
        scan_phase3<<<g1, 256, 0, stream>>>(DT, XC, BM, CM, XZ, e1_A_log, e2_A_log,
                                            e1_D, e2_D, HIN, YB);
    }

    // K6: out-proj GEMM + residual -> d_out  (M=12800, N=96, K=192)
    {
        dim3 g(PROWS / 32, 96 / 32, 2);
        gemm_k<<<g, 256, 0, stream>>>(YB, YB + (size_t)PROWS * DI,
                                      e1_out_w, e2_out_w,
                                      x1, x2,
                                      out, out + (size_t)PROWS * 96,
                                      PROWS, 96, 192);
    }
}

// Round 2
// 425.257 us; speedup vs baseline: 1.1224x; 1.1224x over previous
//
#include <hip/hip_runtime.h>
#include <math.h>

#define PROWS 12800      // B*N rows per stream (B=2, N=6400)
#define NSEQ  6400
#define DI    192
#define DSTATE 16
#define LC    64         // scan chunk length
#define NCHUNK 100       // NSEQ / LC

__device__ __forceinline__ float sigmoidf_(float x) { return 1.0f / (1.0f + __expf(-x)); }

// ---------------------------------------------------------------------------
// K1: LayerNorm both streams + token swap + channel shuffle. (unchanged)
// ---------------------------------------------------------------------------
__global__ void ln_swap_shuffle(const float* __restrict__ x1, const float* __restrict__ x2,
                                const float* __restrict__ g1, const float* __restrict__ b1,
                                const float* __restrict__ g2, const float* __restrict__ b2,
                                float* __restrict__ XS) {
    int r = blockIdx.x;
    int t = threadIdx.x;          // 0..63
    __shared__ float a1[96], a2[96];

    float v10 = x1[r * 96 + t];
    float v20 = x2[r * 96 + t];
    float v11 = 0.f, v21 = 0.f;
    bool has2 = (t < 32);
    if (has2) { v11 = x1[r * 96 + t + 64]; v21 = x2[r * 96 + t + 64]; }

    float s1 = v10 + v11, s2 = v20 + v21;
    float q1 = v10 * v10 + v11 * v11, q2 = v20 * v20 + v21 * v21;
    for (int off = 1; off < 64; off <<= 1) {
        s1 += __shfl_xor(s1, off);
        q1 += __shfl_xor(q1, off);
        s2 += __shfl_xor(s2, off);
        q2 += __shfl_xor(q2, off);
    }
    const float inv96 = 1.0f / 96.0f;
    float m1 = s1 * inv96, m2 = s2 * inv96;
    float i1 = rsqrtf(q1 * inv96 - m1 * m1 + 1e-5f);
    float i2 = rsqrtf(q2 * inv96 - m2 * m2 + 1e-5f);

    a1[t] = (v10 - m1) * i1 * g1[t] + b1[t];
    a2[t] = (v20 - m2) * i2 * g2[t] + b2[t];
    if (has2) {
        a1[t + 64] = (v11 - m1) * i1 * g1[t + 64] + b1[t + 64];
        a2[t + 64] = (v21 - m2) * i2 * g2[t + 64] + b2[t + 64];
    }
    __syncthreads();

    for (int c = t; c < 96; c += 64) {
        int src = (c & 1) * 48 + (c >> 1);
        float vs2 = a2[src];
        float vs1 = (src < 59) ? vs2 : a1[src];
        XS[(size_t)r * 96 + c] = vs1;                       // stream 1 (m=0)
        XS[(size_t)PROWS * 96 + (size_t)r * 96 + c] = vs2;  // stream 2 (m=1)
    }
}

// ---------------------------------------------------------------------------
// K2/K6: tiled GEMM, transposed LDS staging, register blocking.
// O[row,col] = sum_k X[row,k]*W[col,k] (+R). BM=64, BK=32, TM=4.
// template: N (cols), K, BN (col tile), TN (cols/thread, 16*TN == BN).
// ---------------------------------------------------------------------------
template<int N, int K, int BN, int TN>
__global__ __launch_bounds__(256) void gemm_tile(
        const float* __restrict__ X0, const float* __restrict__ X1,
        const float* __restrict__ W0, const float* __restrict__ W1,
        const float* __restrict__ R0, const float* __restrict__ R1,
        float* __restrict__ O0, float* __restrict__ O1) {
    constexpr int BM = 64, BK = 32, TM = 4;
    __shared__ float As[BK][BM + 4];
    __shared__ float Bs[BK][BN + 4];

    int m = blockIdx.z;
    const float* X = m ? X1 : X0;
    const float* W = m ? W1 : W0;
    const float* R = m ? R1 : R0;
    float* O = m ? O1 : O0;

    int tid = threadIdx.x;
    int tx = tid & 15, ty = tid >> 4;
    int row0 = blockIdx.x * BM, col0 = blockIdx.y * BN;

    float acc[TM][TN];
#pragma unroll
    for (int i = 0; i < TM; i++)
#pragma unroll
        for (int j = 0; j < TN; j++) acc[i][j] = 0.f;

    for (int kk = 0; kk < K; kk += BK) {
        for (int q = tid; q < BM * BK / 4; q += 256) {
            int r = q >> 3, k4 = (q & 7) << 2;
            float4 v = *(const float4*)&X[(size_t)(row0 + r) * K + kk + k4];
            As[k4 + 0][r] = v.x; As[k4 + 1][r] = v.y;
            As[k4 + 2][r] = v.z; As[k4 + 3][r] = v.w;
        }
        for (int q = tid; q < BN * BK / 4; q += 256) {
            int n = q >> 3, k4 = (q & 7) << 2;
            float4 v = *(const float4*)&W[(size_t)(col0 + n) * K + kk + k4];
            Bs[k4 + 0][n] = v.x; Bs[k4 + 1][n] = v.y;
            Bs[k4 + 2][n] = v.z; Bs[k4 + 3][n] = v.w;
        }
        __syncthreads();
#pragma unroll
        for (int k = 0; k < BK; k++) {
            float4 a = *(const float4*)&As[k][ty * 4];
            float av[4] = {a.x, a.y, a.z, a.w};
            float bv[TN];
            if constexpr (TN == 4) {
                float4 b = *(const float4*)&Bs[k][tx * 4];
                bv[0] = b.x; bv[1] = b.y; bv[2] = b.z; bv[3] = b.w;
            } else {
                float2 b = *(const float2*)&Bs[k][tx * 2];
                bv[0] = b.x; bv[1] = b.y;
            }
#pragma unroll
            for (int i = 0; i < TM; i++)
#pragma unroll
                for (int j = 0; j < TN; j++) acc[i][j] += av[i] * bv[j];
        }
        __syncthreads();
    }

#pragma unroll
    for (int i = 0; i < TM; i++) {
        int row = row0 + ty * 4 + i;
        size_t base = (size_t)row * N + col0 + tx * TN;
        if constexpr (TN == 4) {
            float4 o4 = make_float4(acc[i][0], acc[i][1], acc[i][2], acc[i][3]);
            if (R) {
                float4 r4 = *(const float4*)&R[base];
                o4.x += r4.x; o4.y += r4.y; o4.z += r4.z; o4.w += r4.w;
            }
            *(float4*)&O[base] = o4;
        } else {
            float2 o2 = make_float2(acc[i][0], acc[i][1]);
            if (R) {
                float2 r2 = *(const float2*)&R[base];
                o2.x += r2.x; o2.y += r2.y;
            }
            *(float2*)&O[base] = o2;
        }
    }
}

// ---------------------------------------------------------------------------
// K3: depthwise causal conv1d (k=4) + bias + SiLU, float4 over channels.
// ---------------------------------------------------------------------------
__global__ void conv_silu(const float* __restrict__ XZ,
                          const float* __restrict__ cw0, const float* __restrict__ cw1,
                          const float* __restrict__ cb0, const float* __restrict__ cb1,
                          float* __restrict__ XC) {
    int idx = blockIdx.x * 256 + threadIdx.x;      // 2*PROWS*48 total
    int d4 = idx % 48;
    int r = (idx / 48) % PROWS;
    int m = idx / (48 * PROWS);
    int b = r / NSEQ, n = r % NSEQ;

    const float* cw = (m ? cw1 : cw0);
    const float* cb = (m ? cb1 : cb0);
    const float* base = XZ + (size_t)m * PROWS * 384;
    int d0 = d4 * 4;

    // per-channel taps (row-major [192][4])
    float4 w0 = *(const float4*)&cw[(d0 + 0) * 4];
    float4 w1 = *(const float4*)&cw[(d0 + 1) * 4];
    float4 w2 = *(const float4*)&cw[(d0 + 2) * 4];
    float4 w3 = *(const float4*)&cw[(d0 + 3) * 4];
    float4 acc = *(const float4*)&cb[d0];

#pragma unroll
    for (int k = 0; k < 4; k++) {
        int nn = n - 3 + k;
        if (nn >= 0) {
            float4 v = *(const float4*)&base[(size_t)(b * NSEQ + nn) * 384 + d0];
            float t0 = (k == 0) ? w0.x : (k == 1) ? w0.y : (k == 2) ? w0.z : w0.w;
            float t1 = (k == 0) ? w1.x : (k == 1) ? w1.y : (k == 2) ? w1.z : w1.w;
            float t2 = (k == 0) ? w2.x : (k == 1) ? w2.y : (k == 2) ? w2.z : w2.w;
            float t3 = (k == 0) ? w3.x : (k == 1) ? w3.y : (k == 2) ? w3.z : w3.w;
            acc.x += t0 * v.x; acc.y += t1 * v.y; acc.z += t2 * v.z; acc.w += t3 * v.w;
        }
    }
    float4 o;
    o.x = acc.x * sigmoidf_(acc.x);
    o.y = acc.y * sigmoidf_(acc.y);
    o.z = acc.z * sigmoidf_(acc.z);
    o.w = acc.w * sigmoidf_(acc.w);
    *(float4*)&XC[(size_t)m * PROWS * DI + (size_t)r * DI + d0] = o;
}

// ---------------------------------------------------------------------------
// K4: fused x_dbl + dt. 1 wave / block, 32 rows. Lane = (row = l&31,
// K-half = l>>5); row K-half lives in 24 float4 registers; xproj weights
// stream through L1 as b128; halves combined via shfl_xor(.,32).
// dt fused, stores transposed through LDS for coalesced b128 writes.
// ---------------------------------------------------------------------------
#define XROWS 32
#define XPAD  196
__global__ __launch_bounds__(64) void xdbl_dt(const float* __restrict__ XC,
        const float* __restrict__ xp0, const float* __restrict__ xp1,
        const float* __restrict__ dw0, const float* __restrict__ dw1,
        const float* __restrict__ db0, const float* __restrict__ db1,
        float* __restrict__ DT, float* __restrict__ BM, float* __restrict__ CM) {
    int m = blockIdx.y;
    int r0 = blockIdx.x * XROWS;
    int l = threadIdx.x;          // 0..63
    int row = l & 31, half = l >> 5;

    const float* XCm = XC + (size_t)m * PROWS * DI;
    const float* xp = m ? xp1 : xp0;
    const float* dw = m ? dw1 : dw0;
    const float* db = m ? db1 : db0;
    float* DTm = DT + (size_t)m * PROWS * DI;
    float* BMm = BM + (size_t)m * PROWS * DSTATE;
    float* CMm = CM + (size_t)m * PROWS * DSTATE;

    __shared__ float Xs[XROWS][XPAD];   // staging: 32 rows x 192 (also dt buffer)
    __shared__ float outs[38][XROWS];   // x_dbl outputs

    // stage tile: 32x192 = 1536 quads, 24 per lane, coalesced
#pragma unroll
    for (int i = 0; i < 24; i++) {
        int q = l + i * 64;
        int r = q / 48, c4 = (q % 48) * 4;
        *(float4*)&Xs[r][c4] = *(const float4*)&XCm[(size_t)(r0 + r) * DI + c4];
    }
    __syncthreads();

    // load my row-half into registers
    float4 xr[24];
#pragma unroll
    for (int q = 0; q < 24; q++) xr[q] = *(const float4*)&Xs[row][half * 96 + q * 4];

    // 38 dot products of length 192 (each lane does its 96-half)
    for (int o = 0; o < 38; o++) {
        const float4* wq = (const float4*)(xp + o * 192 + half * 96);
        float acc = 0.f;
#pragma unroll
        for (int q = 0; q < 24; q++) {
            float4 w = wq[q];
            acc += w.x * xr[q].x + w.y * xr[q].y + w.z * xr[q].z + w.w * xr[q].w;
        }
        acc += __shfl_xor(acc, 32);
        if (l < 32) outs[o][l] = acc;
    }
    __syncthreads();

    // B/C flush: 32x16 tiles, coalesced b128
#pragma unroll
    for (int i = 0; i < 2; i++) {
        int q = i * 64 + l;
        int r = q >> 2, c4 = (q & 3) << 2;
        float4 vb = make_float4(outs[6 + c4][r], outs[7 + c4][r], outs[8 + c4][r], outs[9 + c4][r]);
        float4 vc = make_float4(outs[22 + c4][r], outs[23 + c4][r], outs[24 + c4][r], outs[25 + c4][r]);
        *(float4*)&BMm[(size_t)(r0 + r) * DSTATE + c4] = vb;
        *(float4*)&CMm[(size_t)(r0 + r) * DSTATE + c4] = vc;
    }

    // dt = softplus(dt_w @ x_dbl[:6] + dt_b): 32 rows x 192 d = 96 per lane
    __syncthreads();   // all lanes done reading Xs into regs (it is; reuse ok)
    for (int i = 0; i < 96; i++) {
        int lin = i * 64 + l;          // 0..6143
        int d = lin % DI;
        int r = lin / DI;
        float acc = db[d];
#pragma unroll
        for (int k = 0; k < 6; k++) acc += dw[d * 6 + k] * outs[k][r];
        float sp = fmaxf(acc, 0.f) + log1pf(__expf(-fabsf(acc)));
        Xs[r][d] = sp;
    }
    __syncthreads();
#pragma unroll
    for (int i = 0; i < 24; i++) {
        int q = l + i * 64;
        int r = q / 48, c4 = (q % 48) * 4;
        *(float4*)&DTm[(size_t)(r0 + r) * DI + c4] = *(const float4*)&Xs[r][c4];
    }
}

// ---------------------------------------------------------------------------
// K5a: chunk-local scan (h_in = 0). (unchanged)
// ---------------------------------------------------------------------------
__global__ void scan_phase1(const float* __restrict__ DT, const float* __restrict__ XC,
                            const float* __restrict__ BMp,
                            const float* __restrict__ Al0, const float* __restrict__ Al1,
                            float* __restrict__ HEND, float* __restrict__ DTSUM) {
    int ck = blockIdx.x;
    int dg = blockIdx.y;
    int mb = blockIdx.z;
    int m = mb >> 1, b = mb & 1;
    int tid = threadIdx.x;
    int dl = tid >> 4, s = tid & 15;
    int d = dg * 16 + dl;

    __shared__ float dtb[LC][16], xb[LC][16], Bb[LC][16];
    int r0 = b * NSEQ + ck * LC;
    const float* DTm = DT + (size_t)m * PROWS * DI;
    const float* XCm = XC + (size_t)m * PROWS * DI;
    const float* BMm = BMp + (size_t)m * PROWS * DSTATE;
    for (int i = tid; i < LC * 16; i += 256) {
        int t = i >> 4, j = i & 15;
        dtb[t][j] = DTm[(size_t)(r0 + t) * DI + dg * 16 + j];
        xb[t][j]  = XCm[(size_t)(r0 + t) * DI + dg * 16 + j];
        Bb[t][j]  = BMm[(size_t)(r0 + t) * DSTATE + j];
    }
    __syncthreads();

    const float* Al = m ? Al1 : Al0;
    float a = -expf(Al[d * DSTATE + s]);
    float h = 0.f, dts = 0.f;
#pragma unroll 4
    for (int t = 0; t < LC; t++) {
        float dtv = dtb[t][dl];
        float xv  = xb[t][dl];
        float bv  = Bb[t][s];
        h = __expf(dtv * a) * h + dtv * xv * bv;
        dts += dtv;
    }
    HEND[(((size_t)mb * NCHUNK + ck) * DI + d) * DSTATE + s] = h;
    if (s == 0) DTSUM[((size_t)mb * NCHUNK + ck) * DI + d] = dts;
}

// ---------------------------------------------------------------------------
// K5b: sequential combine over chunks. (unchanged)
// ---------------------------------------------------------------------------
__global__ void scan_combine(const float* __restrict__ HEND, const float* __restrict__ DTSUM,
                             const float* __restrict__ Al0, const float* __restrict__ Al1,
                             float* __restrict__ HIN) {
    int idx = blockIdx.x * 256 + threadIdx.x;  // 0..12287
    int s = idx & 15;
    int d = (idx >> 4) % DI;
    int mb = idx / (DI * DSTATE);
    int m = mb >> 1;
    const float* Al = m ? Al1 : Al0;
    float a = -expf(Al[d * DSTATE + s]);
    float h = 0.f;
    size_t base = (size_t)mb * NCHUNK;
    HIN[((base + 0) * DI + d) * DSTATE + s] = 0.f;
    for (int k = 1; k < NCHUNK; k++) {
        float dts = DTSUM[(base + k - 1) * DI + d];
        h = __expf(a * dts) * h + HEND[((base + k - 1) * DI + d) * DSTATE + s];
        HIN[((base + k) * DI + d) * DSTATE + s] = h;
    }
}

// ---------------------------------------------------------------------------
// K5c: chunk re-scan from h_in; y = sum_s h*C; D-skip + SiLU(z). (unchanged)
// ---------------------------------------------------------------------------
__global__ void scan_phase3(const float* __restrict__ DT, const float* __restrict__ XC,
                            const float* __restrict__ BMp, const float* __restrict__ CMp,
                            const float* __restrict__ XZ,
                            const float* __restrict__ Al0, const float* __restrict__ Al1,
                            const float* __restrict__ D0, const float* __restrict__ D1,
                            const float* __restrict__ HIN, float* __restrict__ YB) {
    int ck = blockIdx.x;
    int dg = blockIdx.y;
    int mb = blockIdx.z;
    int m = mb >> 1, b = mb & 1;
    int tid = threadIdx.x;
    int dl = tid >> 4, s = tid & 15;
    int d = dg * 16 + dl;

    __shared__ float dtb[LC][16], xb[LC][16], Bb[LC][16], Cb[LC][16], zb[LC][16], yt[LC][16];
    int r0 = b * NSEQ + ck * LC;
    const float* DTm = DT + (size_t)m * PROWS * DI;
    const float* XCm = XC + (size_t)m * PROWS * DI;
    const float* BMm = BMp + (size_t)m * PROWS * DSTATE;
    const float* CMm = CMp + (size_t)m * PROWS * DSTATE;
    const float* XZm = XZ + (size_t)m * PROWS * 384;
    for (int i = tid; i < LC * 16; i += 256) {
        int t = i >> 4, j = i & 15;
        dtb[t][j] = DTm[(size_t)(r0 + t) * DI + dg * 16 + j];
        xb[t][j]  = XCm[(size_t)(r0 + t) * DI + dg * 16 + j];
        Bb[t][j]  = BMm[(size_t)(r0 + t) * DSTATE + j];
        Cb[t][j]  = CMm[(size_t)(r0 + t) * DSTATE + j];
        zb[t][j]  = XZm[(size_t)(r0 + t) * 384 + DI + dg * 16 + j];
    }
    __syncthreads();

    const float* Al = m ? Al1 : Al0;
    float a = -expf(Al[d * DSTATE + s]);
    float Dv = (m ? D1 : D0)[d];
    float h = HIN[(((size_t)mb * NCHUNK + ck) * DI + d) * DSTATE + s];

    for (int t = 0; t < LC; t++) {
        float dtv = dtb[t][dl];
        float xv  = xb[t][dl];
        float bv  = Bb[t][s];
        h = __expf(dtv * a) * h + dtv * xv * bv;
        float p = h * Cb[t][s];
        p += __shfl_xor(p, 1);
        p += __shfl_xor(p, 2);
        p += __shfl_xor(p, 4);
        p += __shfl_xor(p, 8);
        if (s == 0) {
            float zv = zb[t][dl];
            yt[t][dl] = (p + xv * Dv) * (zv * sigmoidf_(zv));
        }
    }
    __syncthreads();
    float* YBm = YB + (size_t)m * PROWS * DI;
    for (int i = tid; i < LC * 16; i += 256) {
        int t = i >> 4, j = i & 15;
        YBm[(size_t)(r0 + t) * DI + dg * 16 + j] = yt[t][j];
    }
}

// ---------------------------------------------------------------------------
extern "C" void kernel_launch(void* const* d_in, const int* in_sizes, int n_in,
                              void* d_out, int out_size, void* d_ws, size_t ws_size,
                              hipStream_t stream) {
    const float* x1    = (const float*)d_in[0];
    const float* x2    = (const float*)d_in[1];
    const float* ln1_g = (const float*)d_in[2];
    const float* ln1_b = (const float*)d_in[3];
    const float* ln2_g = (const float*)d_in[4];
    const float* ln2_b = (const float*)d_in[5];
    const float* e1_in_w    = (const float*)d_in[6];
    const float* e1_conv_w  = (const float*)d_in[7];
    const float* e1_conv_b  = (const float*)d_in[8];
    const float* e1_xproj_w = (const float*)d_in[9];
    const float* e1_dt_w    = (const float*)d_in[10];
    const float* e1_dt_b    = (const float*)d_in[11];
    const float* e1_A_log   = (const float*)d_in[12];
    const float* e1_D       = (const float*)d_in[13];
    const float* e1_out_w   = (const float*)d_in[14];
    const float* e2_in_w    = (const float*)d_in[15];
    const float* e2_conv_w  = (const float*)d_in[16];
    const float* e2_conv_b  = (const float*)d_in[17];
    const float* e2_xproj_w = (const float*)d_in[18];
    const float* e2_dt_w    = (const float*)d_in[19];
    const float* e2_dt_b    = (const float*)d_in[20];
    const float* e2_A_log   = (const float*)d_in[21];
    const float* e2_D       = (const float*)d_in[22];
    const float* e2_out_w   = (const float*)d_in[23];
    float* out = (float*)d_out;

    float* ws = (float*)d_ws;
    float* XS    = ws;                       // [2][P][96]
    float* XZ    = XS + 2457600;             // [2][P][384]
    float* XC    = XZ + 9830400;             // [2][P][192]
    float* DT    = XC + 4915200;             // [2][P][192]
    float* BMw   = DT + 4915200;             // [2][P][16]
    float* CMw   = BMw + 409600;             // [2][P][16]
    float* YB    = CMw + 409600;             // [2][P][192]
    float* HEND  = YB + 4915200;             // [4][100][192][16]
    float* DTSUM = HEND + 1228800;           // [4][100][192]
    float* HIN   = DTSUM + 153600;           // [4][100][192][16]

    // K1
    ln_swap_shuffle<<<PROWS, 64, 0, stream>>>(x1, x2, ln1_g, ln1_b, ln2_g, ln2_b, XS);

    // K2: in-proj (M=12800, N=384, K=96), BN=64, TN=4
    {
        dim3 g(PROWS / 64, 384 / 64, 2);
        gemm_tile<384, 96, 64, 4><<<g, 256, 0, stream>>>(
            XS, XS + (size_t)PROWS * 96, e1_in_w, e2_in_w,
            nullptr, nullptr, XZ, XZ + (size_t)PROWS * 384);
    }

    // K3: conv + SiLU
    conv_silu<<<(2 * PROWS * 48) / 256, 256, 0, stream>>>(XZ, e1_conv_w, e2_conv_w,
                                                          e1_conv_b, e2_conv_b, XC);

    // K4: x_dbl + dt
    {
        dim3 g(PROWS / XROWS, 2);
        xdbl_dt<<<g, 64, 0, stream>>>(XC, e1_xproj_w, e2_xproj_w,
                                      e1_dt_w, e2_dt_w, e1_dt_b, e2_dt_b,
                                      DT, BMw, CMw);
    }

    // K5: chunked scan
    {
        dim3 g1(NCHUNK, DI / 16, 4);
        scan_phase1<<<g1, 256, 0, stream>>>(DT, XC, BMw, e1_A_log, e2_A_log, HEND, DTSUM);
        scan_combine<<<48, 256, 0, stream>>>(HEND, DTSUM, e1_A_log, e2_A_log, HIN);
        scan_phase3<<<g1, 256, 0, stream>>>(DT, XC, BMw, CMw, XZ, e1_A_log, e2_A_log,
                                            e1_D, e2_D, HIN, YB);
    }

    // K6: out-proj (M=12800, N=96, K=192) + residual, BN=32, TN=2
    {
        dim3 g(PROWS / 64, 96 / 32, 2);
        gemm_tile<96, 192, 32, 2><<<g, 256, 0, stream>>>(
            YB, YB + (size_t)PROWS * DI, e1_out_w, e2_out_w,
            x1, x2, out, out + (size_t)PROWS * 96);
    }
}

// Round 3
// 361.088 us; speedup vs baseline: 1.3219x; 1.1777x over previous
//
#include <hip/hip_runtime.h>
#include <math.h>

#define PROWS 12800      // B*N rows per stream (B=2, N=6400)
#define NSEQ  6400
#define DI    192
#define DSTATE 16
#define LC    64         // scan chunk length
#define NCHUNK 100       // NSEQ / LC
#define XDW   64         // padded x_dbl width (38 -> 64)

__device__ __forceinline__ float sigmoidf_(float x) { return 1.0f / (1.0f + __expf(-x)); }
__device__ __forceinline__ float softplusf_(float x) {
    return fmaxf(x, 0.f) + log1pf(__expf(-fabsf(x)));
}

// ---------------------------------------------------------------------------
// K1: LayerNorm both streams + token swap + channel shuffle.
// ---------------------------------------------------------------------------
__global__ void ln_swap_shuffle(const float* __restrict__ x1, const float* __restrict__ x2,
                                const float* __restrict__ g1, const float* __restrict__ b1,
                                const float* __restrict__ g2, const float* __restrict__ b2,
                                float* __restrict__ XS) {
    int r = blockIdx.x;
    int t = threadIdx.x;          // 0..63
    __shared__ float a1[96], a2[96];

    float v10 = x1[r * 96 + t];
    float v20 = x2[r * 96 + t];
    float v11 = 0.f, v21 = 0.f;
    bool has2 = (t < 32);
    if (has2) { v11 = x1[r * 96 + t + 64]; v21 = x2[r * 96 + t + 64]; }

    float s1 = v10 + v11, s2 = v20 + v21;
    float q1 = v10 * v10 + v11 * v11, q2 = v20 * v20 + v21 * v21;
    for (int off = 1; off < 64; off <<= 1) {
        s1 += __shfl_xor(s1, off);
        q1 += __shfl_xor(q1, off);
        s2 += __shfl_xor(s2, off);
        q2 += __shfl_xor(q2, off);
    }
    const float inv96 = 1.0f / 96.0f;
    float m1 = s1 * inv96, m2 = s2 * inv96;
    float i1 = rsqrtf(q1 * inv96 - m1 * m1 + 1e-5f);
    float i2 = rsqrtf(q2 * inv96 - m2 * m2 + 1e-5f);

    a1[t] = (v10 - m1) * i1 * g1[t] + b1[t];
    a2[t] = (v20 - m2) * i2 * g2[t] + b2[t];
    if (has2) {
        a1[t + 64] = (v11 - m1) * i1 * g1[t + 64] + b1[t + 64];
        a2[t + 64] = (v21 - m2) * i2 * g2[t + 64] + b2[t + 64];
    }
    __syncthreads();

    for (int c = t; c < 96; c += 64) {
        int src = (c & 1) * 48 + (c >> 1);
        float vs2 = a2[src];
        float vs1 = (src < 59) ? vs2 : a1[src];
        XS[(size_t)r * 96 + c] = vs1;                       // stream 1 (m=0)
        XS[(size_t)PROWS * 96 + (size_t)r * 96 + c] = vs2;  // stream 2 (m=1)
    }
}

// ---------------------------------------------------------------------------
// K2/K6/K-xdbl: tiled GEMM, transposed LDS staging, register blocking.
// O[row,col] = sum_k X[row,k]*W[col,k] (+R). BM=64, BK=32, TM=4.
// ---------------------------------------------------------------------------
template<int N, int K, int BN, int TN>
__global__ __launch_bounds__(256) void gemm_tile(
        const float* __restrict__ X0, const float* __restrict__ X1,
        const float* __restrict__ W0, const float* __restrict__ W1,
        const float* __restrict__ R0, const float* __restrict__ R1,
        float* __restrict__ O0, float* __restrict__ O1) {
    constexpr int BM = 64, BK = 32, TM = 4;
    __shared__ float As[BK][BM + 4];
    __shared__ float Bs[BK][BN + 4];

    int m = blockIdx.z;
    const float* X = m ? X1 : X0;
    const float* W = m ? W1 : W0;
    const float* R = m ? R1 : R0;
    float* O = m ? O1 : O0;

    int tid = threadIdx.x;
    int tx = tid & 15, ty = tid >> 4;
    int row0 = blockIdx.x * BM, col0 = blockIdx.y * BN;

    float acc[TM][TN];
#pragma unroll
    for (int i = 0; i < TM; i++)
#pragma unroll
        for (int j = 0; j < TN; j++) acc[i][j] = 0.f;

    for (int kk = 0; kk < K; kk += BK) {
        for (int q = tid; q < BM * BK / 4; q += 256) {
            int r = q >> 3, k4 = (q & 7) << 2;
            float4 v = *(const float4*)&X[(size_t)(row0 + r) * K + kk + k4];
            As[k4 + 0][r] = v.x; As[k4 + 1][r] = v.y;
            As[k4 + 2][r] = v.z; As[k4 + 3][r] = v.w;
        }
        for (int q = tid; q < BN * BK / 4; q += 256) {
            int n = q >> 3, k4 = (q & 7) << 2;
            float4 v = *(const float4*)&W[(size_t)(col0 + n) * K + kk + k4];
            Bs[k4 + 0][n] = v.x; Bs[k4 + 1][n] = v.y;
            Bs[k4 + 2][n] = v.z; Bs[k4 + 3][n] = v.w;
        }
        __syncthreads();
#pragma unroll
        for (int k = 0; k < BK; k++) {
            float4 a = *(const float4*)&As[k][ty * 4];
            float av[4] = {a.x, a.y, a.z, a.w};
            float bv[TN];
            if constexpr (TN == 4) {
                float4 b = *(const float4*)&Bs[k][tx * 4];
                bv[0] = b.x; bv[1] = b.y; bv[2] = b.z; bv[3] = b.w;
            } else {
                float2 b = *(const float2*)&Bs[k][tx * 2];
                bv[0] = b.x; bv[1] = b.y;
            }
#pragma unroll
            for (int i = 0; i < TM; i++)
#pragma unroll
                for (int j = 0; j < TN; j++) acc[i][j] += av[i] * bv[j];
        }
        __syncthreads();
    }

#pragma unroll
    for (int i = 0; i < TM; i++) {
        int row = row0 + ty * 4 + i;
        size_t base = (size_t)row * N + col0 + tx * TN;
        if constexpr (TN == 4) {
            float4 o4 = make_float4(acc[i][0], acc[i][1], acc[i][2], acc[i][3]);
            if (R) {
                float4 r4 = *(const float4*)&R[base];
                o4.x += r4.x; o4.y += r4.y; o4.z += r4.z; o4.w += r4.w;
            }
            *(float4*)&O[base] = o4;
        } else {
            float2 o2 = make_float2(acc[i][0], acc[i][1]);
            if (R) {
                float2 r2 = *(const float2*)&R[base];
                o2.x += r2.x; o2.y += r2.y;
            }
            *(float2*)&O[base] = o2;
        }
    }
}

// ---------------------------------------------------------------------------
// K3: depthwise causal conv1d (k=4) + bias + SiLU, float4 over channels.
// ---------------------------------------------------------------------------
__global__ void conv_silu(const float* __restrict__ XZ,
                          const float* __restrict__ cw0, const float* __restrict__ cw1,
                          const float* __restrict__ cb0, const float* __restrict__ cb1,
                          float* __restrict__ XC) {
    int idx = blockIdx.x * 256 + threadIdx.x;      // 2*PROWS*48 total
    int d4 = idx % 48;
    int r = (idx / 48) % PROWS;
    int m = idx / (48 * PROWS);
    int b = r / NSEQ, n = r % NSEQ;

    const float* cw = (m ? cw1 : cw0);
    const float* cb = (m ? cb1 : cb0);
    const float* base = XZ + (size_t)m * PROWS * 384;
    int d0 = d4 * 4;

    float4 w0 = *(const float4*)&cw[(d0 + 0) * 4];
    float4 w1 = *(const float4*)&cw[(d0 + 1) * 4];
    float4 w2 = *(const float4*)&cw[(d0 + 2) * 4];
    float4 w3 = *(const float4*)&cw[(d0 + 3) * 4];
    float4 acc = *(const float4*)&cb[d0];

#pragma unroll
    for (int k = 0; k < 4; k++) {
        int nn = n - 3 + k;
        if (nn >= 0) {
            float4 v = *(const float4*)&base[(size_t)(b * NSEQ + nn) * 384 + d0];
            float t0 = (k == 0) ? w0.x : (k == 1) ? w0.y : (k == 2) ? w0.z : w0.w;
            float t1 = (k == 0) ? w1.x : (k == 1) ? w1.y : (k == 2) ? w1.z : w1.w;
            float t2 = (k == 0) ? w2.x : (k == 1) ? w2.y : (k == 2) ? w2.z : w2.w;
            float t3 = (k == 0) ? w3.x : (k == 1) ? w3.y : (k == 2) ? w3.z : w3.w;
            acc.x += t0 * v.x; acc.y += t1 * v.y; acc.z += t2 * v.z; acc.w += t3 * v.w;
        }
    }
    float4 o;
    o.x = acc.x * sigmoidf_(acc.x);
    o.y = acc.y * sigmoidf_(acc.y);
    o.z = acc.z * sigmoidf_(acc.z);
    o.w = acc.w * sigmoidf_(acc.w);
    *(float4*)&XC[(size_t)m * PROWS * DI + (size_t)r * DI + d0] = o;
}

// ---------------------------------------------------------------------------
// K4a: pack xproj weights [38][192] -> zero-padded [XDW][192], both mambas.
// ---------------------------------------------------------------------------
__global__ void pack_w(const float* __restrict__ xp0, const float* __restrict__ xp1,
                       float* __restrict__ WP) {
    int idx = blockIdx.x * 256 + threadIdx.x;    // 2*XDW*192
    if (idx >= 2 * XDW * 192) return;
    int k = idx % 192;
    int o = (idx / 192) % XDW;
    int m = idx / (192 * XDW);
    const float* xp = m ? xp1 : xp0;
    WP[idx] = (o < 38) ? xp[o * 192 + k] : 0.f;
}

// ---------------------------------------------------------------------------
// K5a: chunk-local scan (h_in = 0); dt recomputed from XDBL during staging.
// Block = 256 = 16 d x 16 s; one (chunk, d-group) per block.
// ---------------------------------------------------------------------------
__global__ __launch_bounds__(256) void scan_phase1(
        const float* __restrict__ XDBL, const float* __restrict__ XC,
        const float* __restrict__ dw0, const float* __restrict__ dw1,
        const float* __restrict__ db0, const float* __restrict__ db1,
        const float* __restrict__ Al0, const float* __restrict__ Al1,
        float* __restrict__ HEND, float* __restrict__ DTSUM) {
    int ck = blockIdx.x;
    int dg = blockIdx.y;
    int mb = blockIdx.z;
    int m = mb >> 1, b = mb & 1;
    int tid = threadIdx.x;
    int dl = tid >> 4, s = tid & 15;
    int d = dg * 16 + dl;

    __shared__ float xd6[LC][8];
    __shared__ float dtb[LC][16], xb[LC][16], Bb[LC][16];
    int r0 = b * NSEQ + ck * LC;
    const float* XDm = XDBL + (size_t)m * PROWS * XDW;
    const float* XCm = XC + (size_t)m * PROWS * DI;
    const float* dw = m ? dw1 : dw0;
    const float* db = m ? db1 : db0;

    for (int i = tid; i < LC * 8; i += 256) {
        int t = i >> 3, k = i & 7;
        if (k < 6) xd6[t][k] = XDm[(size_t)(r0 + t) * XDW + k];
    }
    for (int i = tid; i < LC * 16; i += 256) {
        int t = i >> 4, j = i & 15;
        xb[t][j] = XCm[(size_t)(r0 + t) * DI + dg * 16 + j];
        Bb[t][j] = XDm[(size_t)(r0 + t) * XDW + 6 + j];
    }
    __syncthreads();
    for (int i = tid; i < LC * 16; i += 256) {
        int t = i >> 4, j = i & 15;
        int dd = dg * 16 + j;
        float acc = db[dd];
#pragma unroll
        for (int k = 0; k < 6; k++) acc += dw[dd * 6 + k] * xd6[t][k];
        dtb[t][j] = softplusf_(acc);
    }
    __syncthreads();

    const float* Al = m ? Al1 : Al0;
    float a = -expf(Al[d * DSTATE + s]);
    float h = 0.f, dts = 0.f;
#pragma unroll 4
    for (int t = 0; t < LC; t++) {
        float dtv = dtb[t][dl];
        float xv  = xb[t][dl];
        float bv  = Bb[t][s];
        h = __expf(dtv * a) * h + dtv * xv * bv;
        dts += dtv;
    }
    HEND[(((size_t)mb * NCHUNK + ck) * DI + d) * DSTATE + s] = h;
    if (s == 0) DTSUM[((size_t)mb * NCHUNK + ck) * DI + d] = dts;
}

// ---------------------------------------------------------------------------
// K5b: sequential combine over chunks.
// ---------------------------------------------------------------------------
__global__ void scan_combine(const float* __restrict__ HEND, const float* __restrict__ DTSUM,
                             const float* __restrict__ Al0, const float* __restrict__ Al1,
                             float* __restrict__ HIN) {
    int idx = blockIdx.x * 256 + threadIdx.x;  // 0..12287
    int s = idx & 15;
    int d = (idx >> 4) % DI;
    int mb = idx / (DI * DSTATE);
    int m = mb >> 1;
    const float* Al = m ? Al1 : Al0;
    float a = -expf(Al[d * DSTATE + s]);
    float h = 0.f;
    size_t base = (size_t)mb * NCHUNK;
    HIN[((base + 0) * DI + d) * DSTATE + s] = 0.f;
    for (int k = 1; k < NCHUNK; k++) {
        float dts = DTSUM[(base + k - 1) * DI + d];
        h = __expf(a * dts) * h + HEND[((base + k - 1) * DI + d) * DSTATE + s];
        HIN[((base + k) * DI + d) * DSTATE + s] = h;
    }
}

// ---------------------------------------------------------------------------
// K5c: chunk re-scan from h_in; y = sum_s h*C; D-skip + SiLU(z) gating.
// dt recomputed from XDBL (identical arithmetic to phase1).
// ---------------------------------------------------------------------------
__global__ __launch_bounds__(256) void scan_phase3(
        const float* __restrict__ XDBL, const float* __restrict__ XC,
        const float* __restrict__ XZ,
        const float* __restrict__ dw0, const float* __restrict__ dw1,
        const float* __restrict__ db0, const float* __restrict__ db1,
        const float* __restrict__ Al0, const float* __restrict__ Al1,
        const float* __restrict__ D0, const float* __restrict__ D1,
        const float* __restrict__ HIN, float* __restrict__ YB) {
    int ck = blockIdx.x;
    int dg = blockIdx.y;
    int mb = blockIdx.z;
    int m = mb >> 1, b = mb & 1;
    int tid = threadIdx.x;
    int dl = tid >> 4, s = tid & 15;
    int d = dg * 16 + dl;

    __shared__ float xd6[LC][8];
    __shared__ float dtb[LC][16], xb[LC][16], Bb[LC][16], Cb[LC][16], zb[LC][16], yt[LC][16];
    int r0 = b * NSEQ + ck * LC;
    const float* XDm = XDBL + (size_t)m * PROWS * XDW;
    const float* XCm = XC + (size_t)m * PROWS * DI;
    const float* XZm = XZ + (size_t)m * PROWS * 384;
    const float* dw = m ? dw1 : dw0;
    const float* db = m ? db1 : db0;

    for (int i = tid; i < LC * 8; i += 256) {
        int t = i >> 3, k = i & 7;
        if (k < 6) xd6[t][k] = XDm[(size_t)(r0 + t) * XDW + k];
    }
    for (int i = tid; i < LC * 16; i += 256) {
        int t = i >> 4, j = i & 15;
        xb[t][j] = XCm[(size_t)(r0 + t) * DI + dg * 16 + j];
        Bb[t][j] = XDm[(size_t)(r0 + t) * XDW + 6 + j];
        Cb[t][j] = XDm[(size_t)(r0 + t) * XDW + 22 + j];
        zb[t][j] = XZm[(size_t)(r0 + t) * 384 + DI + dg * 16 + j];
    }
    __syncthreads();
    for (int i = tid; i < LC * 16; i += 256) {
        int t = i >> 4, j = i & 15;
        int dd = dg * 16 + j;
        float acc = db[dd];
#pragma unroll
        for (int k = 0; k < 6; k++) acc += dw[dd * 6 + k] * xd6[t][k];
        dtb[t][j] = softplusf_(acc);
    }
    __syncthreads();

    const float* Al = m ? Al1 : Al0;
    float a = -expf(Al[d * DSTATE + s]);
    float Dv = (m ? D1 : D0)[d];
    float h = HIN[(((size_t)mb * NCHUNK + ck) * DI + d) * DSTATE + s];

    for (int t = 0; t < LC; t++) {
        float dtv = dtb[t][dl];
        float xv  = xb[t][dl];
        float bv  = Bb[t][s];
        h = __expf(dtv * a) * h + dtv * xv * bv;
        float p = h * Cb[t][s];
        p += __shfl_xor(p, 1);
        p += __shfl_xor(p, 2);
        p += __shfl_xor(p, 4);
        p += __shfl_xor(p, 8);
        if (s == 0) {
            float zv = zb[t][dl];
            yt[t][dl] = (p + xv * Dv) * (zv * sigmoidf_(zv));
        }
    }
    __syncthreads();
    float* YBm = YB + (size_t)m * PROWS * DI;
    for (int i = tid; i < LC * 16; i += 256) {
        int t = i >> 4, j = i & 15;
        YBm[(size_t)(r0 + t) * DI + dg * 16 + j] = yt[t][j];
    }
}

// ---------------------------------------------------------------------------
extern "C" void kernel_launch(void* const* d_in, const int* in_sizes, int n_in,
                              void* d_out, int out_size, void* d_ws, size_t ws_size,
                              hipStream_t stream) {
    const float* x1    = (const float*)d_in[0];
    const float* x2    = (const float*)d_in[1];
    const float* ln1_g = (const float*)d_in[2];
    const float* ln1_b = (const float*)d_in[3];
    const float* ln2_g = (const float*)d_in[4];
    const float* ln2_b = (const float*)d_in[5];
    const float* e1_in_w    = (const float*)d_in[6];
    const float* e1_conv_w  = (const float*)d_in[7];
    const float* e1_conv_b  = (const float*)d_in[8];
    const float* e1_xproj_w = (const float*)d_in[9];
    const float* e1_dt_w    = (const float*)d_in[10];
    const float* e1_dt_b    = (const float*)d_in[11];
    const float* e1_A_log   = (const float*)d_in[12];
    const float* e1_D       = (const float*)d_in[13];
    const float* e1_out_w   = (const float*)d_in[14];
    const float* e2_in_w    = (const float*)d_in[15];
    const float* e2_conv_w  = (const float*)d_in[16];
    const float* e2_conv_b  = (const float*)d_in[17];
    const float* e2_xproj_w = (const float*)d_in[18];
    const float* e2_dt_w    = (const float*)d_in[19];
    const float* e2_dt_b    = (const float*)d_in[20];
    const float* e2_A_log   = (const float*)d_in[21];
    const float* e2_D       = (const float*)d_in[22];
    const float* e2_out_w   = (const float*)d_in[23];
    float* out = (float*)d_out;

    float* ws = (float*)d_ws;
    float* XS    = ws;                       // [2][P][96]     2,457,600
    float* XZ    = XS + 2457600;             // [2][P][384]    9,830,400
    float* XC    = XZ + 9830400;             // [2][P][192]    4,915,200
    float* XDBL  = XC + 4915200;             // [2][P][64]     1,638,400
    float* WP    = XDBL + 1638400;           // [2][64][192]      24,576
    float* YB    = WP + 24576;               // [2][P][192]    4,915,200
    float* HEND  = YB + 4915200;             // [4][100][192][16] 1,228,800
    float* DTSUM = HEND + 1228800;           // [4][100][192]    153,600
    float* HIN   = DTSUM + 153600;           // [4][100][192][16] 1,228,800

    // K1: LN + swap + shuffle
    ln_swap_shuffle<<<PROWS, 64, 0, stream>>>(x1, x2, ln1_g, ln1_b, ln2_g, ln2_b, XS);

    // K2: in-proj GEMM (M=12800, N=384, K=96)
    {
        dim3 g(PROWS / 64, 384 / 64, 2);
        gemm_tile<384, 96, 64, 4><<<g, 256, 0, stream>>>(
            XS, XS + (size_t)PROWS * 96, e1_in_w, e2_in_w,
            nullptr, nullptr, XZ, XZ + (size_t)PROWS * 384);
    }

    // K3: conv + SiLU
    conv_silu<<<(2 * PROWS * 48) / 256, 256, 0, stream>>>(XZ, e1_conv_w, e2_conv_w,
                                                          e1_conv_b, e2_conv_b, XC);

    // K4: pack weights + x_dbl GEMM (M=12800, N=64(38), K=192)
    pack_w<<<(2 * XDW * 192 + 255) / 256, 256, 0, stream>>>(e1_xproj_w, e2_xproj_w, WP);
    {
        dim3 g(PROWS / 64, 1, 2);
        gemm_tile<XDW, 192, 64, 4><<<g, 256, 0, stream>>>(
            XC, XC + (size_t)PROWS * DI, WP, WP + XDW * 192,
            nullptr, nullptr, XDBL, XDBL + (size_t)PROWS * XDW);
    }

    // K5: chunked scan (dt fused)
    {
        dim3 g1(NCHUNK, DI / 16, 4);
        scan_phase1<<<g1, 256, 0, stream>>>(XDBL, XC, e1_dt_w, e2_dt_w, e1_dt_b, e2_dt_b,
                                            e1_A_log, e2_A_log, HEND, DTSUM);
        scan_combine<<<48, 256, 0, stream>>>(HEND, DTSUM, e1_A_log, e2_A_log, HIN);
        scan_phase3<<<g1, 256, 0, stream>>>(XDBL, XC, XZ, e1_dt_w, e2_dt_w, e1_dt_b, e2_dt_b,
                                            e1_A_log, e2_A_log, e1_D, e2_D, HIN, YB);
    }

    // K6: out-proj GEMM (M=12800, N=96, K=192) + residual
    {
        dim3 g(PROWS / 64, 96 / 32, 2);
        gemm_tile<96, 192, 32, 2><<<g, 256, 0, stream>>>(
            YB, YB + (size_t)PROWS * DI, e1_out_w, e2_out_w,
            x1, x2, out, out + (size_t)PROWS * 96);
    }
}

// Round 4
// 356.030 us; speedup vs baseline: 1.3407x; 1.0142x over previous
//
#include <hip/hip_runtime.h>
#include <math.h>

#define PROWS 12800      // B*N rows per stream (B=2, N=6400)
#define NSEQ  6400
#define DI    192
#define DSTATE 16
#define LC    64         // scan chunk length
#define NCHUNK 100       // NSEQ / LC
#define XDW   64         // padded x_dbl width (38 -> 64)

__device__ __forceinline__ float sigmoidf_(float x) { return 1.0f / (1.0f + __expf(-x)); }
__device__ __forceinline__ float softplusf_(float x) {
    return fmaxf(x, 0.f) + log1pf(__expf(-fabsf(x)));
}

// ---------------------------------------------------------------------------
// K1: LayerNorm both streams + token swap + channel shuffle.
// ---------------------------------------------------------------------------
__global__ void ln_swap_shuffle(const float* __restrict__ x1, const float* __restrict__ x2,
                                const float* __restrict__ g1, const float* __restrict__ b1,
                                const float* __restrict__ g2, const float* __restrict__ b2,
                                float* __restrict__ XS) {
    int r = blockIdx.x;
    int t = threadIdx.x;          // 0..63
    __shared__ float a1[96], a2[96];

    float v10 = x1[r * 96 + t];
    float v20 = x2[r * 96 + t];
    float v11 = 0.f, v21 = 0.f;
    bool has2 = (t < 32);
    if (has2) { v11 = x1[r * 96 + t + 64]; v21 = x2[r * 96 + t + 64]; }

    float s1 = v10 + v11, s2 = v20 + v21;
    float q1 = v10 * v10 + v11 * v11, q2 = v20 * v20 + v21 * v21;
    for (int off = 1; off < 64; off <<= 1) {
        s1 += __shfl_xor(s1, off);
        q1 += __shfl_xor(q1, off);
        s2 += __shfl_xor(s2, off);
        q2 += __shfl_xor(q2, off);
    }
    const float inv96 = 1.0f / 96.0f;
    float m1 = s1 * inv96, m2 = s2 * inv96;
    float i1 = rsqrtf(q1 * inv96 - m1 * m1 + 1e-5f);
    float i2 = rsqrtf(q2 * inv96 - m2 * m2 + 1e-5f);

    a1[t] = (v10 - m1) * i1 * g1[t] + b1[t];
    a2[t] = (v20 - m2) * i2 * g2[t] + b2[t];
    if (has2) {
        a1[t + 64] = (v11 - m1) * i1 * g1[t + 64] + b1[t + 64];
        a2[t + 64] = (v21 - m2) * i2 * g2[t + 64] + b2[t + 64];
    }
    __syncthreads();

    for (int c = t; c < 96; c += 64) {
        int src = (c & 1) * 48 + (c >> 1);
        float vs2 = a2[src];
        float vs1 = (src < 59) ? vs2 : a1[src];
        XS[(size_t)r * 96 + c] = vs1;                       // stream 1 (m=0)
        XS[(size_t)PROWS * 96 + (size_t)r * 96 + c] = vs2;  // stream 2 (m=1)
    }
}

// ---------------------------------------------------------------------------
// K2/K6/K-xdbl: tiled GEMM, transposed LDS staging, register blocking.
// ---------------------------------------------------------------------------
template<int N, int K, int BN, int TN>
__global__ __launch_bounds__(256) void gemm_tile(
        const float* __restrict__ X0, const float* __restrict__ X1,
        const float* __restrict__ W0, const float* __restrict__ W1,
        const float* __restrict__ R0, const float* __restrict__ R1,
        float* __restrict__ O0, float* __restrict__ O1) {
    constexpr int BM = 64, BK = 32, TM = 4;
    __shared__ float As[BK][BM + 4];
    __shared__ float Bs[BK][BN + 4];

    int m = blockIdx.z;
    const float* X = m ? X1 : X0;
    const float* W = m ? W1 : W0;
    const float* R = m ? R1 : R0;
    float* O = m ? O1 : O0;

    int tid = threadIdx.x;
    int tx = tid & 15, ty = tid >> 4;
    int row0 = blockIdx.x * BM, col0 = blockIdx.y * BN;

    float acc[TM][TN];
#pragma unroll
    for (int i = 0; i < TM; i++)
#pragma unroll
        for (int j = 0; j < TN; j++) acc[i][j] = 0.f;

    for (int kk = 0; kk < K; kk += BK) {
        for (int q = tid; q < BM * BK / 4; q += 256) {
            int r = q >> 3, k4 = (q & 7) << 2;
            float4 v = *(const float4*)&X[(size_t)(row0 + r) * K + kk + k4];
            As[k4 + 0][r] = v.x; As[k4 + 1][r] = v.y;
            As[k4 + 2][r] = v.z; As[k4 + 3][r] = v.w;
        }
        for (int q = tid; q < BN * BK / 4; q += 256) {
            int n = q >> 3, k4 = (q & 7) << 2;
            float4 v = *(const float4*)&W[(size_t)(col0 + n) * K + kk + k4];
            Bs[k4 + 0][n] = v.x; Bs[k4 + 1][n] = v.y;
            Bs[k4 + 2][n] = v.z; Bs[k4 + 3][n] = v.w;
        }
        __syncthreads();
#pragma unroll
        for (int k = 0; k < BK; k++) {
            float4 a = *(const float4*)&As[k][ty * 4];
            float av[4] = {a.x, a.y, a.z, a.w};
            float bv[TN];
            if constexpr (TN == 4) {
                float4 b = *(const float4*)&Bs[k][tx * 4];
                bv[0] = b.x; bv[1] = b.y; bv[2] = b.z; bv[3] = b.w;
            } else {
                float2 b = *(const float2*)&Bs[k][tx * 2];
                bv[0] = b.x; bv[1] = b.y;
            }
#pragma unroll
            for (int i = 0; i < TM; i++)
#pragma unroll
                for (int j = 0; j < TN; j++) acc[i][j] += av[i] * bv[j];
        }
        __syncthreads();
    }

#pragma unroll
    for (int i = 0; i < TM; i++) {
        int row = row0 + ty * 4 + i;
        size_t base = (size_t)row * N + col0 + tx * TN;
        if constexpr (TN == 4) {
            float4 o4 = make_float4(acc[i][0], acc[i][1], acc[i][2], acc[i][3]);
            if (R) {
                float4 r4 = *(const float4*)&R[base];
                o4.x += r4.x; o4.y += r4.y; o4.z += r4.z; o4.w += r4.w;
            }
            *(float4*)&O[base] = o4;
        } else {
            float2 o2 = make_float2(acc[i][0], acc[i][1]);
            if (R) {
                float2 r2 = *(const float2*)&R[base];
                o2.x += r2.x; o2.y += r2.y;
            }
            *(float2*)&O[base] = o2;
        }
    }
}

// ---------------------------------------------------------------------------
// K3: depthwise causal conv1d (k=4) + bias + SiLU, float4 over channels.
// ---------------------------------------------------------------------------
__global__ void conv_silu(const float* __restrict__ XZ,
                          const float* __restrict__ cw0, const float* __restrict__ cw1,
                          const float* __restrict__ cb0, const float* __restrict__ cb1,
                          float* __restrict__ XC) {
    int idx = blockIdx.x * 256 + threadIdx.x;      // 2*PROWS*48 total
    int d4 = idx % 48;
    int r = (idx / 48) % PROWS;
    int m = idx / (48 * PROWS);
    int b = r / NSEQ, n = r % NSEQ;

    const float* cw = (m ? cw1 : cw0);
    const float* cb = (m ? cb1 : cb0);
    const float* base = XZ + (size_t)m * PROWS * 384;
    int d0 = d4 * 4;

    float4 w0 = *(const float4*)&cw[(d0 + 0) * 4];
    float4 w1 = *(const float4*)&cw[(d0 + 1) * 4];
    float4 w2 = *(const float4*)&cw[(d0 + 2) * 4];
    float4 w3 = *(const float4*)&cw[(d0 + 3) * 4];
    float4 acc = *(const float4*)&cb[d0];

#pragma unroll
    for (int k = 0; k < 4; k++) {
        int nn = n - 3 + k;
        if (nn >= 0) {
            float4 v = *(const float4*)&base[(size_t)(b * NSEQ + nn) * 384 + d0];
            float t0 = (k == 0) ? w0.x : (k == 1) ? w0.y : (k == 2) ? w0.z : w0.w;
            float t1 = (k == 0) ? w1.x : (k == 1) ? w1.y : (k == 2) ? w1.z : w1.w;
            float t2 = (k == 0) ? w2.x : (k == 1) ? w2.y : (k == 2) ? w2.z : w2.w;
            float t3 = (k == 0) ? w3.x : (k == 1) ? w3.y : (k == 2) ? w3.z : w3.w;
            acc.x += t0 * v.x; acc.y += t1 * v.y; acc.z += t2 * v.z; acc.w += t3 * v.w;
        }
    }
    float4 o;
    o.x = acc.x * sigmoidf_(acc.x);
    o.y = acc.y * sigmoidf_(acc.y);
    o.z = acc.z * sigmoidf_(acc.z);
    o.w = acc.w * sigmoidf_(acc.w);
    *(float4*)&XC[(size_t)m * PROWS * DI + (size_t)r * DI + d0] = o;
}

// ---------------------------------------------------------------------------
// K4a: pack xproj weights [38][192] -> zero-padded [XDW][192], both mambas.
// ---------------------------------------------------------------------------
__global__ void pack_w(const float* __restrict__ xp0, const float* __restrict__ xp1,
                       float* __restrict__ WP) {
    int idx = blockIdx.x * 256 + threadIdx.x;    // 2*XDW*192
    if (idx >= 2 * XDW * 192) return;
    int k = idx % 192;
    int o = (idx / 192) % XDW;
    int m = idx / (192 * XDW);
    const float* xp = m ? xp1 : xp0;
    WP[idx] = (o < 38) ? xp[o * 192 + k] : 0.f;
}

// ---------------------------------------------------------------------------
// K5a: chunk-local scan, thread = d-channel, h[16] in registers.
// B/x_dbl6 rows are wave-uniform -> scalar loads; x is coalesced + prefetched.
// One wave per block; grid (NCHUNK, 3, 4).
// ---------------------------------------------------------------------------
__global__ __launch_bounds__(64) void scan_phase1(
        const float* __restrict__ XDBL, const float* __restrict__ XC,
        const float* __restrict__ dw0, const float* __restrict__ dw1,
        const float* __restrict__ db0, const float* __restrict__ db1,
        const float* __restrict__ Al0, const float* __restrict__ Al1,
        float* __restrict__ HEND, float* __restrict__ DTSUM) {
    int ck = blockIdx.x;
    int dg = blockIdx.y;          // 0..2
    int mb = blockIdx.z;
    int m = mb >> 1, b = mb & 1;
    int d = dg * 64 + threadIdx.x;
    int r0 = b * NSEQ + ck * LC;

    const float* XDm = XDBL + (size_t)m * PROWS * XDW;
    const float* XCm = XC + (size_t)m * PROWS * DI;
    const float* dw = (m ? dw1 : dw0) + d * 6;
    float dbv = (m ? db1 : db0)[d];
    const float* Al = (m ? Al1 : Al0) + d * DSTATE;

    float dwv[6];
#pragma unroll
    for (int k = 0; k < 6; k++) dwv[k] = dw[k];
    float a[DSTATE], h[DSTATE];
#pragma unroll
    for (int s = 0; s < DSTATE; s++) { a[s] = -expf(Al[s]); h[s] = 0.f; }

    float dts = 0.f;
    float xv = XCm[(size_t)r0 * DI + d];
#pragma unroll 2
    for (int t = 0; t < LC; t++) {
        const float* xd = XDm + (size_t)(r0 + t) * XDW;   // wave-uniform row
        float acc = dbv;
#pragma unroll
        for (int k = 0; k < 6; k++) acc += dwv[k] * xd[k];
        float dtv = softplusf_(acc);
        dts += dtv;
        float w = dtv * xv;
        float xv_n = (t + 1 < LC) ? XCm[(size_t)(r0 + t + 1) * DI + d] : 0.f;
#pragma unroll
        for (int s = 0; s < DSTATE; s++)
            h[s] = __expf(dtv * a[s]) * h[s] + w * xd[6 + s];
        xv = xv_n;
    }
    float* he = HEND + (((size_t)mb * NCHUNK + ck) * DI + d) * DSTATE;
#pragma unroll
    for (int s4 = 0; s4 < 4; s4++)
        *(float4*)&he[s4 * 4] = make_float4(h[s4 * 4], h[s4 * 4 + 1], h[s4 * 4 + 2], h[s4 * 4 + 3]);
    DTSUM[((size_t)mb * NCHUNK + ck) * DI + d] = dts;
}

// ---------------------------------------------------------------------------
// K5b: sequential combine over chunks. (unchanged)
// ---------------------------------------------------------------------------
__global__ void scan_combine(const float* __restrict__ HEND, const float* __restrict__ DTSUM,
                             const float* __restrict__ Al0, const float* __restrict__ Al1,
                             float* __restrict__ HIN) {
    int idx = blockIdx.x * 256 + threadIdx.x;  // 0..12287
    int s = idx & 15;
    int d = (idx >> 4) % DI;
    int mb = idx / (DI * DSTATE);
    int m = mb >> 1;
    const float* Al = m ? Al1 : Al0;
    float a = -expf(Al[d * DSTATE + s]);
    float h = 0.f;
    size_t base = (size_t)mb * NCHUNK;
    HIN[((base + 0) * DI + d) * DSTATE + s] = 0.f;
    for (int k = 1; k < NCHUNK; k++) {
        float dts = DTSUM[(base + k - 1) * DI + d];
        h = __expf(a * dts) * h + HEND[((base + k - 1) * DI + d) * DSTATE + s];
        HIN[((base + k) * DI + d) * DSTATE + s] = h;
    }
}

// ---------------------------------------------------------------------------
// K5c: chunk re-scan from h_in, thread = d-channel, h[16] + y in registers.
// y = sum_s h*C (register fmac, no shuffles) + D-skip + SiLU(z) gating.
// ---------------------------------------------------------------------------
__global__ __launch_bounds__(64) void scan_phase3(
        const float* __restrict__ XDBL, const float* __restrict__ XC,
        const float* __restrict__ XZ,
        const float* __restrict__ dw0, const float* __restrict__ dw1,
        const float* __restrict__ db0, const float* __restrict__ db1,
        const float* __restrict__ Al0, const float* __restrict__ Al1,
        const float* __restrict__ D0, const float* __restrict__ D1,
        const float* __restrict__ HIN, float* __restrict__ YB) {
    int ck = blockIdx.x;
    int dg = blockIdx.y;
    int mb = blockIdx.z;
    int m = mb >> 1, b = mb & 1;
    int d = dg * 64 + threadIdx.x;
    int r0 = b * NSEQ + ck * LC;

    const float* XDm = XDBL + (size_t)m * PROWS * XDW;
    const float* XCm = XC + (size_t)m * PROWS * DI;
    const float* XZm = XZ + (size_t)m * PROWS * 384;
    const float* dw = (m ? dw1 : dw0) + d * 6;
    float dbv = (m ? db1 : db0)[d];
    const float* Al = (m ? Al1 : Al0) + d * DSTATE;
    float Dv = (m ? D1 : D0)[d];
    float* YBm = YB + (size_t)m * PROWS * DI;

    float dwv[6];
#pragma unroll
    for (int k = 0; k < 6; k++) dwv[k] = dw[k];
    float a[DSTATE], h[DSTATE];
#pragma unroll
    for (int s = 0; s < DSTATE; s++) a[s] = -expf(Al[s]);
    const float* hi = HIN + (((size_t)mb * NCHUNK + ck) * DI + d) * DSTATE;
#pragma unroll
    for (int s4 = 0; s4 < 4; s4++) {
        float4 v = *(const float4*)&hi[s4 * 4];
        h[s4 * 4] = v.x; h[s4 * 4 + 1] = v.y; h[s4 * 4 + 2] = v.z; h[s4 * 4 + 3] = v.w;
    }

    float xv = XCm[(size_t)r0 * DI + d];
    float zv = XZm[(size_t)r0 * 384 + DI + d];
#pragma unroll 2
    for (int t = 0; t < LC; t++) {
        const float* xd = XDm + (size_t)(r0 + t) * XDW;   // wave-uniform row
        float acc = dbv;
#pragma unroll
        for (int k = 0; k < 6; k++) acc += dwv[k] * xd[k];
        float dtv = softplusf_(acc);
        float w = dtv * xv;
        float xv_n = 0.f, zv_n = 0.f;
        if (t + 1 < LC) {
            xv_n = XCm[(size_t)(r0 + t + 1) * DI + d];
            zv_n = XZm[(size_t)(r0 + t + 1) * 384 + DI + d];
        }
        float y0 = 0.f, y1 = 0.f, y2 = 0.f, y3 = 0.f;
#pragma unroll
        for (int s = 0; s < DSTATE; s += 4) {
            h[s + 0] = __expf(dtv * a[s + 0]) * h[s + 0] + w * xd[6 + s + 0];
            h[s + 1] = __expf(dtv * a[s + 1]) * h[s + 1] + w * xd[6 + s + 1];
            h[s + 2] = __expf(dtv * a[s + 2]) * h[s + 2] + w * xd[6 + s + 2];
            h[s + 3] = __expf(dtv * a[s + 3]) * h[s + 3] + w * xd[6 + s + 3];
            y0 += h[s + 0] * xd[22 + s + 0];
            y1 += h[s + 1] * xd[22 + s + 1];
            y2 += h[s + 2] * xd[22 + s + 2];
            y3 += h[s + 3] * xd[22 + s + 3];
        }
        float p = (y0 + y1) + (y2 + y3);
        float yv = (p + xv * Dv) * (zv * sigmoidf_(zv));
        YBm[(size_t)(r0 + t) * DI + d] = yv;
        xv = xv_n; zv = zv_n;
    }
}

// ---------------------------------------------------------------------------
extern "C" void kernel_launch(void* const* d_in, const int* in_sizes, int n_in,
                              void* d_out, int out_size, void* d_ws, size_t ws_size,
                              hipStream_t stream) {
    const float* x1    = (const float*)d_in[0];
    const float* x2    = (const float*)d_in[1];
    const float* ln1_g = (const float*)d_in[2];
    const float* ln1_b = (const float*)d_in[3];
    const float* ln2_g = (const float*)d_in[4];
    const float* ln2_b = (const float*)d_in[5];
    const float* e1_in_w    = (const float*)d_in[6];
    const float* e1_conv_w  = (const float*)d_in[7];
    const float* e1_conv_b  = (const float*)d_in[8];
    const float* e1_xproj_w = (const float*)d_in[9];
    const float* e1_dt_w    = (const float*)d_in[10];
    const float* e1_dt_b    = (const float*)d_in[11];
    const float* e1_A_log   = (const float*)d_in[12];
    const float* e1_D       = (const float*)d_in[13];
    const float* e1_out_w   = (const float*)d_in[14];
    const float* e2_in_w    = (const float*)d_in[15];
    const float* e2_conv_w  = (const float*)d_in[16];
    const float* e2_conv_b  = (const float*)d_in[17];
    const float* e2_xproj_w = (const float*)d_in[18];
    const float* e2_dt_w    = (const float*)d_in[19];
    const float* e2_dt_b    = (const float*)d_in[20];
    const float* e2_A_log   = (const float*)d_in[21];
    const float* e2_D       = (const float*)d_in[22];
    const float* e2_out_w   = (const float*)d_in[23];
    float* out = (float*)d_out;

    float* ws = (float*)d_ws;
    float* XS    = ws;                       // [2][P][96]     2,457,600
    float* XZ    = XS + 2457600;             // [2][P][384]    9,830,400
    float* XC    = XZ + 9830400;             // [2][P][192]    4,915,200
    float* XDBL  = XC + 4915200;             // [2][P][64]     1,638,400
    float* WP    = XDBL + 1638400;           // [2][64][192]      24,576
    float* YB    = WP + 24576;               // [2][P][192]    4,915,200
    float* HEND  = YB + 4915200;             // [4][100][192][16] 1,228,800
    float* DTSUM = HEND + 1228800;           // [4][100][192]    153,600
    float* HIN   = DTSUM + 153600;           // [4][100][192][16] 1,228,800

    // K1: LN + swap + shuffle
    ln_swap_shuffle<<<PROWS, 64, 0, stream>>>(x1, x2, ln1_g, ln1_b, ln2_g, ln2_b, XS);

    // K2: in-proj GEMM (M=12800, N=384, K=96)
    {
        dim3 g(PROWS / 64, 384 / 64, 2);
        gemm_tile<384, 96, 64, 4><<<g, 256, 0, stream>>>(
            XS, XS + (size_t)PROWS * 96, e1_in_w, e2_in_w,
            nullptr, nullptr, XZ, XZ + (size_t)PROWS * 384);
    }

    // K3: conv + SiLU
    conv_silu<<<(2 * PROWS * 48) / 256, 256, 0, stream>>>(XZ, e1_conv_w, e2_conv_w,
                                                          e1_conv_b, e2_conv_b, XC);

    // K4: pack weights + x_dbl GEMM (M=12800, N=64(38), K=192)
    pack_w<<<(2 * XDW * 192 + 255) / 256, 256, 0, stream>>>(e1_xproj_w, e2_xproj_w, WP);
    {
        dim3 g(PROWS / 64, 1, 2);
        gemm_tile<XDW, 192, 64, 4><<<g, 256, 0, stream>>>(
            XC, XC + (size_t)PROWS * DI, WP, WP + XDW * 192,
            nullptr, nullptr, XDBL, XDBL + (size_t)PROWS * XDW);
    }

    // K5: chunked scan (register-state formulation)
    {
        dim3 g1(NCHUNK, DI / 64, 4);
        scan_phase1<<<g1, 64, 0, stream>>>(XDBL, XC, e1_dt_w, e2_dt_w, e1_dt_b, e2_dt_b,
                                           e1_A_log, e2_A_log, HEND, DTSUM);
        scan_combine<<<48, 256, 0, stream>>>(HEND, DTSUM, e1_A_log, e2_A_log, HIN);
        scan_phase3<<<g1, 64, 0, stream>>>(XDBL, XC, XZ, e1_dt_w, e2_dt_w, e1_dt_b, e2_dt_b,
                                           e1_A_log, e2_A_log, e1_D, e2_D, HIN, YB);
    }

    // K6: out-proj GEMM (M=12800, N=96, K=192) + residual
    {
        dim3 g(PROWS / 64, 96 / 32, 2);
        gemm_tile<96, 192, 32, 2><<<g, 256, 0, stream>>>(
            YB, YB + (size_t)PROWS * DI, e1_out_w, e2_out_w,
            x1, x2, out, out + (size_t)PROWS * 96);
    }
}

// Round 5
// 341.599 us; speedup vs baseline: 1.3973x; 1.0422x over previous
//
#include <hip/hip_runtime.h>
#include <math.h>

#define PROWS 12800      // B*N rows per stream (B=2, N=6400)
#define NSEQ  6400
#define DI    192
#define DSTATE 16
#define LC    32         // scan chunk length
#define NCHUNK 200       // NSEQ / LC
#define XDW   64         // padded x_dbl width (aligned layout: 0-5 dt, 8-23 B, 24-39 C)

__device__ __forceinline__ float sigmoidf_(float x) { return 1.0f / (1.0f + __expf(-x)); }
__device__ __forceinline__ float softplusf_(float x) {
    return fmaxf(x, 0.f) + log1pf(__expf(-fabsf(x)));
}

// ---------------------------------------------------------------------------
// K1: LayerNorm both streams + token swap + channel shuffle.
// ---------------------------------------------------------------------------
__global__ void ln_swap_shuffle(const float* __restrict__ x1, const float* __restrict__ x2,
                                const float* __restrict__ g1, const float* __restrict__ b1,
                                const float* __restrict__ g2, const float* __restrict__ b2,
                                float* __restrict__ XS) {
    int r = blockIdx.x;
    int t = threadIdx.x;          // 0..63
    __shared__ float a1[96], a2[96];

    float v10 = x1[r * 96 + t];
    float v20 = x2[r * 96 + t];
    float v11 = 0.f, v21 = 0.f;
    bool has2 = (t < 32);
    if (has2) { v11 = x1[r * 96 + t + 64]; v21 = x2[r * 96 + t + 64]; }

    float s1 = v10 + v11, s2 = v20 + v21;
    float q1 = v10 * v10 + v11 * v11, q2 = v20 * v20 + v21 * v21;
    for (int off = 1; off < 64; off <<= 1) {
        s1 += __shfl_xor(s1, off);
        q1 += __shfl_xor(q1, off);
        s2 += __shfl_xor(s2, off);
        q2 += __shfl_xor(q2, off);
    }
    const float inv96 = 1.0f / 96.0f;
    float m1 = s1 * inv96, m2 = s2 * inv96;
    float i1 = rsqrtf(q1 * inv96 - m1 * m1 + 1e-5f);
    float i2 = rsqrtf(q2 * inv96 - m2 * m2 + 1e-5f);

    a1[t] = (v10 - m1) * i1 * g1[t] + b1[t];
    a2[t] = (v20 - m2) * i2 * g2[t] + b2[t];
    if (has2) {
        a1[t + 64] = (v11 - m1) * i1 * g1[t + 64] + b1[t + 64];
        a2[t + 64] = (v21 - m2) * i2 * g2[t + 64] + b2[t + 64];
    }
    __syncthreads();

    for (int c = t; c < 96; c += 64) {
        int src = (c & 1) * 48 + (c >> 1);
        float vs2 = a2[src];
        float vs1 = (src < 59) ? vs2 : a1[src];
        XS[(size_t)r * 96 + c] = vs1;                       // stream 1 (m=0)
        XS[(size_t)PROWS * 96 + (size_t)r * 96 + c] = vs2;  // stream 2 (m=1)
    }
}

// ---------------------------------------------------------------------------
// K2/K6/K-xdbl: tiled GEMM, transposed LDS staging, register blocking.
// ---------------------------------------------------------------------------
template<int N, int K, int BN, int TN>
__global__ __launch_bounds__(256) void gemm_tile(
        const float* __restrict__ X0, const float* __restrict__ X1,
        const float* __restrict__ W0, const float* __restrict__ W1,
        const float* __restrict__ R0, const float* __restrict__ R1,
        float* __restrict__ O0, float* __restrict__ O1) {
    constexpr int BM = 64, BK = 32, TM = 4;
    __shared__ float As[BK][BM + 4];
    __shared__ float Bs[BK][BN + 4];

    int m = blockIdx.z;
    const float* X = m ? X1 : X0;
    const float* W = m ? W1 : W0;
    const float* R = m ? R1 : R0;
    float* O = m ? O1 : O0;

    int tid = threadIdx.x;
    int tx = tid & 15, ty = tid >> 4;
    int row0 = blockIdx.x * BM, col0 = blockIdx.y * BN;

    float acc[TM][TN];
#pragma unroll
    for (int i = 0; i < TM; i++)
#pragma unroll
        for (int j = 0; j < TN; j++) acc[i][j] = 0.f;

    for (int kk = 0; kk < K; kk += BK) {
        for (int q = tid; q < BM * BK / 4; q += 256) {
            int r = q >> 3, k4 = (q & 7) << 2;
            float4 v = *(const float4*)&X[(size_t)(row0 + r) * K + kk + k4];
            As[k4 + 0][r] = v.x; As[k4 + 1][r] = v.y;
            As[k4 + 2][r] = v.z; As[k4 + 3][r] = v.w;
        }
        for (int q = tid; q < BN * BK / 4; q += 256) {
            int n = q >> 3, k4 = (q & 7) << 2;
            float4 v = *(const float4*)&W[(size_t)(col0 + n) * K + kk + k4];
            Bs[k4 + 0][n] = v.x; Bs[k4 + 1][n] = v.y;
            Bs[k4 + 2][n] = v.z; Bs[k4 + 3][n] = v.w;
        }
        __syncthreads();
#pragma unroll
        for (int k = 0; k < BK; k++) {
            float4 a = *(const float4*)&As[k][ty * 4];
            float av[4] = {a.x, a.y, a.z, a.w};
            float bv[TN];
            if constexpr (TN == 4) {
                float4 b = *(const float4*)&Bs[k][tx * 4];
                bv[0] = b.x; bv[1] = b.y; bv[2] = b.z; bv[3] = b.w;
            } else {
                float2 b = *(const float2*)&Bs[k][tx * 2];
                bv[0] = b.x; bv[1] = b.y;
            }
#pragma unroll
            for (int i = 0; i < TM; i++)
#pragma unroll
                for (int j = 0; j < TN; j++) acc[i][j] += av[i] * bv[j];
        }
        __syncthreads();
    }

#pragma unroll
    for (int i = 0; i < TM; i++) {
        int row = row0 + ty * 4 + i;
        size_t base = (size_t)row * N + col0 + tx * TN;
        if constexpr (TN == 4) {
            float4 o4 = make_float4(acc[i][0], acc[i][1], acc[i][2], acc[i][3]);
            if (R) {
                float4 r4 = *(const float4*)&R[base];
                o4.x += r4.x; o4.y += r4.y; o4.z += r4.z; o4.w += r4.w;
            }
            *(float4*)&O[base] = o4;
        } else {
            float2 o2 = make_float2(acc[i][0], acc[i][1]);
            if (R) {
                float2 r2 = *(const float2*)&R[base];
                o2.x += r2.x; o2.y += r2.y;
            }
            *(float2*)&O[base] = o2;
        }
    }
}

// ---------------------------------------------------------------------------
// K3: depthwise causal conv1d (k=4) + bias + SiLU, float4 over channels.
// ---------------------------------------------------------------------------
__global__ void conv_silu(const float* __restrict__ XZ,
                          const float* __restrict__ cw0, const float* __restrict__ cw1,
                          const float* __restrict__ cb0, const float* __restrict__ cb1,
                          float* __restrict__ XC) {
    int idx = blockIdx.x * 256 + threadIdx.x;      // 2*PROWS*48 total
    int d4 = idx % 48;
    int r = (idx / 48) % PROWS;
    int m = idx / (48 * PROWS);
    int b = r / NSEQ, n = r % NSEQ;

    const float* cw = (m ? cw1 : cw0);
    const float* cb = (m ? cb1 : cb0);
    const float* base = XZ + (size_t)m * PROWS * 384;
    int d0 = d4 * 4;

    float4 w0 = *(const float4*)&cw[(d0 + 0) * 4];
    float4 w1 = *(const float4*)&cw[(d0 + 1) * 4];
    float4 w2 = *(const float4*)&cw[(d0 + 2) * 4];
    float4 w3 = *(const float4*)&cw[(d0 + 3) * 4];
    float4 acc = *(const float4*)&cb[d0];

#pragma unroll
    for (int k = 0; k < 4; k++) {
        int nn = n - 3 + k;
        if (nn >= 0) {
            float4 v = *(const float4*)&base[(size_t)(b * NSEQ + nn) * 384 + d0];
            float t0 = (k == 0) ? w0.x : (k == 1) ? w0.y : (k == 2) ? w0.z : w0.w;
            float t1 = (k == 0) ? w1.x : (k == 1) ? w1.y : (k == 2) ? w1.z : w1.w;
            float t2 = (k == 0) ? w2.x : (k == 1) ? w2.y : (k == 2) ? w2.z : w2.w;
            float t3 = (k == 0) ? w3.x : (k == 1) ? w3.y : (k == 2) ? w3.z : w3.w;
            acc.x += t0 * v.x; acc.y += t1 * v.y; acc.z += t2 * v.z; acc.w += t3 * v.w;
        }
    }
    float4 o;
    o.x = acc.x * sigmoidf_(acc.x);
    o.y = acc.y * sigmoidf_(acc.y);
    o.z = acc.z * sigmoidf_(acc.z);
    o.w = acc.w * sigmoidf_(acc.w);
    *(float4*)&XC[(size_t)m * PROWS * DI + (size_t)r * DI + d0] = o;
}

// ---------------------------------------------------------------------------
// K4a: pack xproj weights [38][192] into aligned layout [XDW][192]:
//   out col 0..5  = dt_r rows 0..5    (cols 6,7 zero)
//   out col 8..23 = B rows 6..21
//   out col 24..39= C rows 22..37     (cols 40..63 zero)
// ---------------------------------------------------------------------------
__global__ void pack_w(const float* __restrict__ xp0, const float* __restrict__ xp1,
                       float* __restrict__ WP) {
    int idx = blockIdx.x * 256 + threadIdx.x;    // 2*XDW*192
    if (idx >= 2 * XDW * 192) return;
    int k = idx % 192;
    int o = (idx / 192) % XDW;
    int m = idx / (192 * XDW);
    const float* xp = m ? xp1 : xp0;
    float v = 0.f;
    if (o < 6) v = xp[o * 192 + k];
    else if (o >= 8 && o < 40) v = xp[(o - 2) * 192 + k];
    WP[idx] = v;
}

// ---------------------------------------------------------------------------
// K5a: chunk-local scan. Block = 192 threads = all d; one (mb,chunk)/block.
// x_dbl chunk staged to LDS (broadcast b128 reads in loop); h[16] in regs.
// HEND layout [mb][ck][s][d] for coalesced state I/O.
// ---------------------------------------------------------------------------
__global__ __launch_bounds__(192) void scan_phase1(
        const float* __restrict__ XDBL, const float* __restrict__ XC,
        const float* __restrict__ dw0, const float* __restrict__ dw1,
        const float* __restrict__ db0, const float* __restrict__ db1,
        const float* __restrict__ Al0, const float* __restrict__ Al1,
        float* __restrict__ HEND, float* __restrict__ DTSUM) {
    int ck = blockIdx.x;          // 0..NCHUNK-1
    int mb = blockIdx.y;          // m*2+b
    int m = mb >> 1, b = mb & 1;
    int d = threadIdx.x;          // 0..191
    int r0 = b * NSEQ + ck * LC;

    __shared__ float4 xds[LC][16];   // 32 rows x 64 floats

    const float* XDm = XDBL + (size_t)m * PROWS * XDW;
    const float* XCm = XC + (size_t)m * PROWS * DI;

    for (int q = d; q < LC * 16; q += 192) {
        int t = q >> 4, c = q & 15;
        xds[t][c] = ((const float4*)(XDm + (size_t)(r0 + t) * XDW))[c];
    }

    const float* dw = (m ? dw1 : dw0) + d * 6;
    float dbv = (m ? db1 : db0)[d];
    const float* Al = (m ? Al1 : Al0) + d * DSTATE;
    float dwv[6];
#pragma unroll
    for (int k = 0; k < 6; k++) dwv[k] = dw[k];
    float a[DSTATE], h[DSTATE];
#pragma unroll
    for (int s = 0; s < DSTATE; s++) { a[s] = -expf(Al[s]); h[s] = 0.f; }

    float xv = XCm[(size_t)r0 * DI + d];
    float dts = 0.f;
    __syncthreads();

#pragma unroll 4
    for (int t = 0; t < LC; t++) {
        float4 q0 = xds[t][0], q1 = xds[t][1];
        float4 B0 = xds[t][2], B1 = xds[t][3], B2 = xds[t][4], B3 = xds[t][5];
        float acc = dbv + dwv[0] * q0.x + dwv[1] * q0.y + dwv[2] * q0.z
                        + dwv[3] * q0.w + dwv[4] * q1.x + dwv[5] * q1.y;
        float dtv = softplusf_(acc);
        dts += dtv;
        float w = dtv * xv;
        float xv_n = (t + 1 < LC) ? XCm[(size_t)(r0 + t + 1) * DI + d] : 0.f;
        h[0]  = __expf(dtv * a[0])  * h[0]  + w * B0.x;
        h[1]  = __expf(dtv * a[1])  * h[1]  + w * B0.y;
        h[2]  = __expf(dtv * a[2])  * h[2]  + w * B0.z;
        h[3]  = __expf(dtv * a[3])  * h[3]  + w * B0.w;
        h[4]  = __expf(dtv * a[4])  * h[4]  + w * B1.x;
        h[5]  = __expf(dtv * a[5])  * h[5]  + w * B1.y;
        h[6]  = __expf(dtv * a[6])  * h[6]  + w * B1.z;
        h[7]  = __expf(dtv * a[7])  * h[7]  + w * B1.w;
        h[8]  = __expf(dtv * a[8])  * h[8]  + w * B2.x;
        h[9]  = __expf(dtv * a[9])  * h[9]  + w * B2.y;
        h[10] = __expf(dtv * a[10]) * h[10] + w * B2.z;
        h[11] = __expf(dtv * a[11]) * h[11] + w * B2.w;
        h[12] = __expf(dtv * a[12]) * h[12] + w * B3.x;
        h[13] = __expf(dtv * a[13]) * h[13] + w * B3.y;
        h[14] = __expf(dtv * a[14]) * h[14] + w * B3.z;
        h[15] = __expf(dtv * a[15]) * h[15] + w * B3.w;
        xv = xv_n;
    }

    size_t hb = (((size_t)mb * NCHUNK + ck) * DSTATE) * DI + d;
#pragma unroll
    for (int s = 0; s < DSTATE; s++) HEND[hb + (size_t)s * DI] = h[s];
    DTSUM[((size_t)mb * NCHUNK + ck) * DI + d] = dts;
}

// ---------------------------------------------------------------------------
// K5b: sequential combine over chunks. Lane = d (coalesced).
// ---------------------------------------------------------------------------
__global__ void scan_combine(const float* __restrict__ HEND, const float* __restrict__ DTSUM,
                             const float* __restrict__ Al0, const float* __restrict__ Al1,
                             float* __restrict__ HIN) {
    int idx = blockIdx.x * 256 + threadIdx.x;  // 0..12287
    int d = idx % DI;
    int s = (idx / DI) % DSTATE;
    int mb = idx / (DI * DSTATE);
    int m = mb >> 1;
    const float* Al = m ? Al1 : Al0;
    float a = -expf(Al[d * DSTATE + s]);
    float h = 0.f;
    size_t cb = (size_t)mb * NCHUNK;
    HIN[((cb + 0) * DSTATE + s) * DI + d] = 0.f;
    for (int k = 1; k < NCHUNK; k++) {
        float dts = DTSUM[(cb + k - 1) * DI + d];
        h = __expf(a * dts) * h + HEND[((cb + k - 1) * DSTATE + s) * DI + d];
        HIN[((cb + k) * DSTATE + s) * DI + d] = h;
    }
}

// ---------------------------------------------------------------------------
// K5c: chunk re-scan from h_in; y = sum_s h*C; D-skip + SiLU(z) gating.
// ---------------------------------------------------------------------------
__global__ __launch_bounds__(192) void scan_phase3(
        const float* __restrict__ XDBL, const float* __restrict__ XC,
        const float* __restrict__ XZ,
        const float* __restrict__ dw0, const float* __restrict__ dw1,
        const float* __restrict__ db0, const float* __restrict__ db1,
        const float* __restrict__ Al0, const float* __restrict__ Al1,
        const float* __restrict__ D0, const float* __restrict__ D1,
        const float* __restrict__ HIN, float* __restrict__ YB) {
    int ck = blockIdx.x;
    int mb = blockIdx.y;
    int m = mb >> 1, b = mb & 1;
    int d = threadIdx.x;          // 0..191
    int r0 = b * NSEQ + ck * LC;

    __shared__ float4 xds[LC][16];

    const float* XDm = XDBL + (size_t)m * PROWS * XDW;
    const float* XCm = XC + (size_t)m * PROWS * DI;
    const float* XZm = XZ + (size_t)m * PROWS * 384;
    float* YBm = YB + (size_t)m * PROWS * DI;

    for (int q = d; q < LC * 16; q += 192) {
        int t = q >> 4, c = q & 15;
        xds[t][c] = ((const float4*)(XDm + (size_t)(r0 + t) * XDW))[c];
    }

    const float* dw = (m ? dw1 : dw0) + d * 6;
    float dbv = (m ? db1 : db0)[d];
    const float* Al = (m ? Al1 : Al0) + d * DSTATE;
    float Dv = (m ? D1 : D0)[d];
    float dwv[6];
#pragma unroll
    for (int k = 0; k < 6; k++) dwv[k] = dw[k];
    float a[DSTATE], h[DSTATE];
#pragma unroll
    for (int s = 0; s < DSTATE; s++) a[s] = -expf(Al[s]);
    size_t hb = (((size_t)mb * NCHUNK + ck) * DSTATE) * DI + d;
#pragma unroll
    for (int s = 0; s < DSTATE; s++) h[s] = HIN[hb + (size_t)s * DI];

    float xv = XCm[(size_t)r0 * DI + d];
    float zv = XZm[(size_t)r0 * 384 + DI + d];
    __syncthreads();

#pragma unroll 4
    for (int t = 0; t < LC; t++) {
        float4 q0 = xds[t][0], q1 = xds[t][1];
        float4 B0 = xds[t][2], B1 = xds[t][3], B2 = xds[t][4], B3 = xds[t][5];
        float4 C0 = xds[t][6], C1 = xds[t][7], C2 = xds[t][8], C3 = xds[t][9];
        float acc = dbv + dwv[0] * q0.x + dwv[1] * q0.y + dwv[2] * q0.z
                        + dwv[3] * q0.w + dwv[4] * q1.x + dwv[5] * q1.y;
        float dtv = softplusf_(acc);
        float w = dtv * xv;
        float xv_n = 0.f, zv_n = 0.f;
        if (t + 1 < LC) {
            xv_n = XCm[(size_t)(r0 + t + 1) * DI + d];
            zv_n = XZm[(size_t)(r0 + t + 1) * 384 + DI + d];
        }
        float y0, y1, y2, y3;
        h[0]  = __expf(dtv * a[0])  * h[0]  + w * B0.x;  y0  = h[0]  * C0.x;
        h[1]  = __expf(dtv * a[1])  * h[1]  + w * B0.y;  y1  = h[1]  * C0.y;
        h[2]  = __expf(dtv * a[2])  * h[2]  + w * B0.z;  y2  = h[2]  * C0.z;
        h[3]  = __expf(dtv * a[3])  * h[3]  + w * B0.w;  y3  = h[3]  * C0.w;
        h[4]  = __expf(dtv * a[4])  * h[4]  + w * B1.x;  y0 += h[4]  * C1.x;
        h[5]  = __expf(dtv * a[5])  * h[5]  + w * B1.y;  y1 += h[5]  * C1.y;
        h[6]  = __expf(dtv * a[6])  * h[6]  + w * B1.z;  y2 += h[6]  * C1.z;
        h[7]  = __expf(dtv * a[7])  * h[7]  + w * B1.w;  y3 += h[7]  * C1.w;
        h[8]  = __expf(dtv * a[8])  * h[8]  + w * B2.x;  y0 += h[8]  * C2.x;
        h[9]  = __expf(dtv * a[9])  * h[9]  + w * B2.y;  y1 += h[9]  * C2.y;
        h[10] = __expf(dtv * a[10]) * h[10] + w * B2.z;  y2 += h[10] * C2.z;
        h[11] = __expf(dtv * a[11]) * h[11] + w * B2.w;  y3 += h[11] * C2.w;
        h[12] = __expf(dtv * a[12]) * h[12] + w * B3.x;  y0 += h[12] * C3.x;
        h[13] = __expf(dtv * a[13]) * h[13] + w * B3.y;  y1 += h[13] * C3.y;
        h[14] = __expf(dtv * a[14]) * h[14] + w * B3.z;  y2 += h[14] * C3.z;
        h[15] = __expf(dtv * a[15]) * h[15] + w * B3.w;  y3 += h[15] * C3.w;
        float p = (y0 + y1) + (y2 + y3);
        float yv = (p + xv * Dv) * (zv * sigmoidf_(zv));
        YBm[(size_t)(r0 + t) * DI + d] = yv;
        xv = xv_n; zv = zv_n;
    }
}

// ---------------------------------------------------------------------------
extern "C" void kernel_launch(void* const* d_in, const int* in_sizes, int n_in,
                              void* d_out, int out_size, void* d_ws, size_t ws_size,
                              hipStream_t stream) {
    const float* x1    = (const float*)d_in[0];
    const float* x2    = (const float*)d_in[1];
    const float* ln1_g = (const float*)d_in[2];
    const float* ln1_b = (const float*)d_in[3];
    const float* ln2_g = (const float*)d_in[4];
    const float* ln2_b = (const float*)d_in[5];
    const float* e1_in_w    = (const float*)d_in[6];
    const float* e1_conv_w  = (const float*)d_in[7];
    const float* e1_conv_b  = (const float*)d_in[8];
    const float* e1_xproj_w = (const float*)d_in[9];
    const float* e1_dt_w    = (const float*)d_in[10];
    const float* e1_dt_b    = (const float*)d_in[11];
    const float* e1_A_log   = (const float*)d_in[12];
    const float* e1_D       = (const float*)d_in[13];
    const float* e1_out_w   = (const float*)d_in[14];
    const float* e2_in_w    = (const float*)d_in[15];
    const float* e2_conv_w  = (const float*)d_in[16];
    const float* e2_conv_b  = (const float*)d_in[17];
    const float* e2_xproj_w = (const float*)d_in[18];
    const float* e2_dt_w    = (const float*)d_in[19];
    const float* e2_dt_b    = (const float*)d_in[20];
    const float* e2_A_log   = (const float*)d_in[21];
    const float* e2_D       = (const float*)d_in[22];
    const float* e2_out_w   = (const float*)d_in[23];
    float* out = (float*)d_out;

    float* ws = (float*)d_ws;
    float* XS    = ws;                       // [2][P][96]     2,457,600 (dead after K2)
    float* XZ    = XS + 2457600;             // [2][P][384]    9,830,400
    float* XC    = XZ + 9830400;             // [2][P][192]    4,915,200
    float* XDBL  = XC + 4915200;             // [2][P][64]     1,638,400
    float* WP    = XDBL + 1638400;           // [2][64][192]      24,576
    float* YB    = WP + 24576;               // [2][P][192]    4,915,200
    float* HIN   = YB + 4915200;             // [4][200][16][192] 2,457,600
    float* DTSUM = HIN + 2457600;            // [4][200][192]    153,600
    float* HEND  = XS;                       // alias: [4][200][16][192] 2,457,600

    // K1: LN + swap + shuffle
    ln_swap_shuffle<<<PROWS, 64, 0, stream>>>(x1, x2, ln1_g, ln1_b, ln2_g, ln2_b, XS);

    // K2: in-proj GEMM (M=12800, N=384, K=96)
    {
        dim3 g(PROWS / 64, 384 / 64, 2);
        gemm_tile<384, 96, 64, 4><<<g, 256, 0, stream>>>(
            XS, XS + (size_t)PROWS * 96, e1_in_w, e2_in_w,
            nullptr, nullptr, XZ, XZ + (size_t)PROWS * 384);
    }

    // K3: conv + SiLU
    conv_silu<<<(2 * PROWS * 48) / 256, 256, 0, stream>>>(XZ, e1_conv_w, e2_conv_w,
                                                          e1_conv_b, e2_conv_b, XC);

    // K4: pack weights + x_dbl GEMM (M=12800, N=64(40), K=192)
    pack_w<<<(2 * XDW * 192 + 255) / 256, 256, 0, stream>>>(e1_xproj_w, e2_xproj_w, WP);
    {
        dim3 g(PROWS / 64, 1, 2);
        gemm_tile<XDW, 192, 64, 4><<<g, 256, 0, stream>>>(
            XC, XC + (size_t)PROWS * DI, WP, WP + XDW * 192,
            nullptr, nullptr, XDBL, XDBL + (size_t)PROWS * XDW);
    }

    // K5: chunked scan (LDS-staged, register-state)
    {
        dim3 g1(NCHUNK, 4);
        scan_phase1<<<g1, 192, 0, stream>>>(XDBL, XC, e1_dt_w, e2_dt_w, e1_dt_b, e2_dt_b,
                                            e1_A_log, e2_A_log, HEND, DTSUM);
        scan_combine<<<48, 256, 0, stream>>>(HEND, DTSUM, e1_A_log, e2_A_log, HIN);
        scan_phase3<<<g1, 192, 0, stream>>>(XDBL, XC, XZ, e1_dt_w, e2_dt_w, e1_dt_b, e2_dt_b,
                                            e1_A_log, e2_A_log, e1_D, e2_D, HIN, YB);
    }

    // K6: out-proj GEMM (M=12800, N=96, K=192) + residual
    {
        dim3 g(PROWS / 64, 96 / 32, 2);
        gemm_tile<96, 192, 32, 2><<<g, 256, 0, stream>>>(
            YB, YB + (size_t)PROWS * DI, e1_out_w, e2_out_w,
            x1, x2, out, out + (size_t)PROWS * 96);
    }
}